// Round 5
// baseline (496.591 us; speedup 1.0000x reference)
//
#include <hip/hip_runtime.h>
#include <math.h>

#define B_ 2
#define N_ 2048
#define D_ 1024
#define H_ 16
#define M_ (B_*N_)

typedef unsigned short u16;
typedef unsigned int u32;
typedef short bf16x8 __attribute__((ext_vector_type(8)));
typedef float f32x4 __attribute__((ext_vector_type(4)));

struct Ptr5 { const float* p[5]; };
struct GammaArg { float lg2[16]; };

static __device__ inline u16 f2bf(float f) {
  union { float f; unsigned u; } x; x.f = f;
  unsigned u = x.u;
  unsigned r = (u + 0x7fffu + ((u >> 16) & 1u)) >> 16;
  return (u16)r;
}
static __device__ inline float bf2f(u16 h) {
  union { unsigned u; float f; } x; x.u = ((unsigned)h) << 16; return x.f;
}
static __device__ inline bf16x8 ld8(const u16* p) {
  uint4 u = *(const uint4*)(p);
  return *reinterpret_cast<bf16x8*>(&u);
}
#define GLDS(g, l) __builtin_amdgcn_global_load_lds((const __attribute__((address_space(1))) u32*)(g), (__attribute__((address_space(3))) u32*)(l), 16, 0, 0)

// ---------- batch stats of x (sum, sumsq) ----------
__global__ void k_batch_stats_partial(const float* __restrict__ x, double* __restrict__ part) {
  int b = blockIdx.y, c = blockIdx.x, t = threadIdx.x;
  const float* p = x + (size_t)b*(N_*D_) + (size_t)c*32768;
  double s = 0.0, s2 = 0.0;
  for (int it = 0; it < 32; ++it) {
    float4 v = *(const float4*)(p + it*1024 + t*4);
    s  += (double)v.x + (double)v.y + (double)v.z + (double)v.w;
    s2 += (double)v.x*v.x + (double)v.y*v.y + (double)v.z*v.z + (double)v.w*v.w;
  }
  for (int o = 32; o > 0; o >>= 1) { s += __shfl_down(s,o); s2 += __shfl_down(s2,o); }
  __shared__ double lds[8];
  int w = t>>6, l = t&63;
  if (l==0) { lds[w*2]=s; lds[w*2+1]=s2; }
  __syncthreads();
  if (t==0) {
    part[(b*64+c)*2]   = lds[0]+lds[2]+lds[4]+lds[6];
    part[(b*64+c)*2+1] = lds[1]+lds[3]+lds[5]+lds[7];
  }
}

__global__ void k_batch_stats_final(const double* __restrict__ part, float* __restrict__ stats) {
  int b = blockIdx.x, t = threadIdx.x; // 64 threads
  double s = part[(b*64+t)*2], s2 = part[(b*64+t)*2+1];
  for (int o = 32; o > 0; o >>= 1) { s += __shfl_down(s,o); s2 += __shfl_down(s2,o); }
  if (t==0) {
    double inv = 1.0/(double)(N_*D_);
    double mu = s*inv, var = s2*inv - mu*mu;
    stats[b*2]   = (float)mu;
    stats[b*2+1] = rsqrtf((float)var + 1e-5f);
  }
}

// ---------- weight abs-mean ----------
__global__ void k_wmean_partial(Ptr5 W, double* __restrict__ part) {
  int wi = blockIdx.y, c = blockIdx.x, t = threadIdx.x;
  const float* p = W.p[wi] + (size_t)c*65536;
  double s = 0.0;
  for (int it = 0; it < 64; ++it) {
    float4 v = *(const float4*)(p + it*1024 + t*4);
    s += fabs((double)v.x)+fabs((double)v.y)+fabs((double)v.z)+fabs((double)v.w);
  }
  for (int o = 32; o > 0; o >>= 1) s += __shfl_down(s,o);
  __shared__ double lds[4];
  if ((t&63)==0) lds[t>>6]=s;
  __syncthreads();
  if (t==0) part[wi*16+c] = lds[0]+lds[1]+lds[2]+lds[3];
}

__global__ void k_wmean_final(const double* __restrict__ part, float* __restrict__ mw, float* __restrict__ invmw) {
  int wi = blockIdx.x, t = threadIdx.x;
  double s = (t<16) ? part[wi*16+t] : 0.0;
  for (int o = 8; o > 0; o >>= 1) s += __shfl_down(s,o);
  if (t==0) {
    double mean = s / (double)(D_*D_);
    float mwc = fmaxf((float)mean, 1e-5f);
    mw[wi] = mwc;
    invmw[wi] = 1.0f/mwc;
  }
}

__global__ void k_ternarize(Ptr5 W, const float* __restrict__ invmw, u16* __restrict__ wt) {
  int wi = blockIdx.y;
  float inv = invmw[wi];
  size_t off = (size_t)blockIdx.x*1024 + threadIdx.x*4;
  float4 v = *(const float4*)(W.p[wi] + off);
  ushort4 o4;
  o4.x = f2bf(fminf(fmaxf(rintf(v.x*inv),-1.f),1.f));
  o4.y = f2bf(fminf(fmaxf(rintf(v.y*inv),-1.f),1.f));
  o4.z = f2bf(fminf(fmaxf(rintf(v.z*inv),-1.f),1.f));
  o4.w = f2bf(fminf(fmaxf(rintf(v.w*inv),-1.f),1.f));
  *(ushort4*)(wt + (size_t)wi*(D_*D_) + off) = o4;
}

// ---------- per-row activation quant (shared LN stats) ----------
__global__ void k_quant_rows(const float* __restrict__ in, const float* __restrict__ stats,
                             u16* __restrict__ q, float* __restrict__ rowscale) {
  int m = blockIdx.x, t = threadIdx.x;
  int b = m >> 11;
  float mu = stats[b*2], rstd = stats[b*2+1];
  float4 v = *(const float4*)(in + (size_t)m*D_ + t*4);
  float xn0 = (v.x-mu)*rstd, xn1 = (v.y-mu)*rstd, xn2 = (v.z-mu)*rstd, xn3 = (v.w-mu)*rstd;
  float am = fmaxf(fmaxf(fabsf(xn0),fabsf(xn1)),fmaxf(fabsf(xn2),fabsf(xn3)));
  for (int o = 32; o > 0; o >>= 1) am = fmaxf(am, __shfl_xor(am,o));
  __shared__ float wm[4];
  int w = t>>6, l = t&63;
  if (l==0) wm[w]=am;
  __syncthreads();
  am = fmaxf(fmaxf(wm[0],wm[1]),fmaxf(wm[2],wm[3]));
  float clipped = fmaxf(am, 1e-5f);
  float sc = 127.0f/clipped;
  ushort4 o4;
  o4.x = f2bf(fminf(fmaxf(rintf(xn0*sc),-128.f),127.f));
  o4.y = f2bf(fminf(fmaxf(rintf(xn1*sc),-128.f),127.f));
  o4.z = f2bf(fminf(fmaxf(rintf(xn2*sc),-128.f),127.f));
  o4.w = f2bf(fminf(fmaxf(rintf(xn3*sc),-128.f),127.f));
  *(ushort4*)(q + (size_t)m*D_ + t*4) = o4;
  if (t==0) rowscale[m] = clipped/127.0f;
}

// ---------- fused q/k/v/g GEMM: 128x128 tile (m97 structure), BK=32 ----------
// Wt = 4 concatenated [1024,1024] ternary matrices -> [4096,1024].
// widx 0: qh [B,H,N,64]; 1: kh [B,H,N,64]; 2: vhT [B,H,64,N]; 3: silu -> gbuf f32.
__global__ __launch_bounds__(256) void k_gemm_qkvg(const u16* __restrict__ A, const u16* __restrict__ Wt,
                       const float* __restrict__ rowscale, const float* __restrict__ mw,
                       u16* __restrict__ qh, u16* __restrict__ kh, u16* __restrict__ vhT,
                       float* __restrict__ gbuf) {
  __shared__ u16 As[128*32];
  __shared__ u16 Bs[128*32];
  int tid = threadIdx.x;
  int m0 = blockIdx.x*128, n0g = blockIdx.y*128;
  int widx = blockIdx.y >> 3;
  int w = tid>>6, l = tid&63;
  int wm = (w>>1)*64, wn = (w&1)*64;
  int lr = l&15, lkg = l>>4;
  f32x4 acc[4][4];
  for (int i=0;i<4;++i) for (int j=0;j<4;++j) acc[i][j] = (f32x4){0.f,0.f,0.f,0.f};
  int c0 = tid, c1 = tid + 256;
  const u16* ga0 = A  + (size_t)(m0 + (c0>>2))*D_ + (c0&3)*8;
  const u16* ga1 = A  + (size_t)(m0 + (c1>>2))*D_ + (c1&3)*8;
  const u16* gb0 = Wt + (size_t)(n0g + (c0>>2))*D_ + (c0&3)*8;
  const u16* gb1 = Wt + (size_t)(n0g + (c1>>2))*D_ + (c1&3)*8;
  for (int k0 = 0; k0 < D_; k0 += 32) {
    __syncthreads();
    GLDS(ga0 + k0, &As[w*512]);
    GLDS(ga1 + k0, &As[2048 + w*512]);
    GLDS(gb0 + k0, &Bs[w*512]);
    GLDS(gb1 + k0, &Bs[2048 + w*512]);
    __syncthreads();
    bf16x8 a[4], b[4];
    #pragma unroll
    for (int i=0;i<4;++i) a[i] = ld8(&As[(wm + i*16 + lr)*32 + lkg*8]);
    #pragma unroll
    for (int j=0;j<4;++j) b[j] = ld8(&Bs[(wn + j*16 + lr)*32 + lkg*8]);
    #pragma unroll
    for (int i=0;i<4;++i)
      #pragma unroll
      for (int j=0;j<4;++j)
        acc[i][j] = __builtin_amdgcn_mfma_f32_16x16x32_bf16(a[i], b[j], acc[i][j], 0, 0, 0);
  }
  float sw = mw[widx];
  for (int i=0;i<4;++i) {
    int rowb = m0 + wm + i*16 + lkg*4;
    int bb = rowb >> 11;
    float rs[4];
    #pragma unroll
    for (int r=0;r<4;++r) rs[r] = rowscale[rowb+r] * sw;
    for (int j=0;j<4;++j) {
      int col_g = n0g + wn + j*16 + lr;
      float vv[4];
      #pragma unroll
      for (int r=0;r<4;++r) vv[r] = acc[i][j][r] * rs[r];
      int h = (col_g >> 6) & 15, e = col_g & 63;
      if (widx == 0) {
        #pragma unroll
        for (int r=0;r<4;++r) {
          int n = (rowb+r) & 2047;
          qh[(((size_t)(bb*H_ + h))*N_ + n)*64 + e] = f2bf(vv[r]);
        }
      } else if (widx == 1) {
        #pragma unroll
        for (int r=0;r<4;++r) {
          int n = (rowb+r) & 2047;
          kh[(((size_t)(bb*H_ + h))*N_ + n)*64 + e] = f2bf(vv[r]);
        }
      } else if (widx == 2) {
        int n4 = rowb & 2047;
        ushort4 pk;
        pk.x = f2bf(vv[0]); pk.y = f2bf(vv[1]); pk.z = f2bf(vv[2]); pk.w = f2bf(vv[3]);
        *(ushort4*)&vhT[(((size_t)(bb*H_ + h))*64 + e)*N_ + n4] = pk;
      } else {
        int colm = col_g & 1023;
        #pragma unroll
        for (int r=0;r<4;++r)
          gbuf[(size_t)(rowb+r)*D_ + colm] = vv[r] / (1.0f + expf(-vv[r]));
      }
    }
  }
}

// ---------- retention phase A: per-chunk state contribution ----------
// M_c[dv][dk] = sum_j gamma^(64-j) * v[c*64+j][dv] * k[c*64+j][dk]   (f32)
__global__ __launch_bounds__(256) void k_state(const u16* __restrict__ kh, const u16* __restrict__ vhT,
                       float* __restrict__ Mbuf, GammaArg G) {
  __shared__ u16 kT[64][72];   // [dk][j]
  int c = blockIdx.x, bh = blockIdx.y;
  float lg = G.lg2[bh & 15];
  int tid = threadIdx.x, w = tid>>6, l = tid&63;
  int lr = l&15, lkg = l>>4;
  const size_t base = (size_t)bh * (N_*64);
  // stage K^T (transpose via LDS)
  {
    int j = tid>>2, cs = (tid&3)*16;
    const u16* kp = kh + base + (size_t)(c*64 + j)*64 + cs;
    uint4 u0 = *(const uint4*)kp;
    uint4 u1 = *(const uint4*)(kp + 8);
    const u16* s0 = (const u16*)&u0;
    const u16* s1 = (const u16*)&u1;
    #pragma unroll
    for (int m2=0;m2<8;++m2) kT[cs+m2][j] = s0[m2];
    #pragma unroll
    for (int m2=0;m2<8;++m2) kT[cs+8+m2][j] = s1[m2];
  }
  __syncthreads();
  // weighted V^T fragments, hi/lo bf16 split
  bf16x8 ah[2], al[2];
  #pragma unroll
  for (int kk=0;kk<2;++kk) {
    bf16x8 raw = ld8(vhT + base + (size_t)(w*16 + lr)*N_ + c*64 + kk*32 + lkg*8);
    #pragma unroll
    for (int m2=0;m2<8;++m2) {
      int j = kk*32 + lkg*8 + m2;
      float wj = exp2f((float)(64 - j) * lg);
      float p = bf2f((u16)raw[m2]) * wj;
      u16 hh = f2bf(p);
      ah[kk][m2] = (short)hh;
      al[kk][m2] = (short)f2bf(p - bf2f(hh));
    }
  }
  f32x4 macc[4];
  for (int t=0;t<4;++t) macc[t] = (f32x4){0.f,0.f,0.f,0.f};
  #pragma unroll
  for (int t=0;t<4;++t)
    #pragma unroll
    for (int kk=0;kk<2;++kk) {
      bf16x8 b = ld8(&kT[t*16 + lr][kk*32 + lkg*8]);
      macc[t] = __builtin_amdgcn_mfma_f32_16x16x32_bf16(ah[kk], b, macc[t], 0,0,0);
      macc[t] = __builtin_amdgcn_mfma_f32_16x16x32_bf16(al[kk], b, macc[t], 0,0,0);
    }
  float* mp = Mbuf + (size_t)(bh*32 + c)*4096;
  for (int t=0;t<4;++t) {
    #pragma unroll
    for (int r=0;r<4;++r)
      mp[(w*16 + lkg*4 + r)*64 + t*16 + lr] = macc[t][r];
  }
}

// ---------- retention scan: S_c = g64*S_{c-1} + M_{c-1}, store bf16 hi/lo ----------
__global__ void k_scan(const float* __restrict__ Mbuf, u16* __restrict__ Shi, u16* __restrict__ Slo, GammaArg G) {
  int bx = blockIdx.x, bh = blockIdx.y;
  float g64 = exp2f(64.0f * G.lg2[bh & 15]);
  int e = bx*256 + threadIdx.x;
  size_t eb = (size_t)bh*32*4096 + e;
  float S = 0.0f;
  Shi[eb] = 0; Slo[eb] = 0;
  #pragma unroll
  for (int c = 1; c < 32; ++c) {
    S = g64*S + Mbuf[eb + (size_t)(c-1)*4096];
    u16 hh = f2bf(S);
    Shi[eb + (size_t)c*4096] = hh;
    Slo[eb + (size_t)c*4096] = f2bf(S - bf2f(hh));
  }
}

// ---------- retention phase B: y = gamma^i * q . S  +  local (masked decay) ----------
__global__ __launch_bounds__(256) void k_retB(const u16* __restrict__ qh, const u16* __restrict__ kh,
                       const u16* __restrict__ vhT, const u16* __restrict__ Shi, const u16* __restrict__ Slo,
                       float* __restrict__ y, GammaArg G) {
  __shared__ u16 pl[4][16][76];
  int c = blockIdx.x, bh = blockIdx.y;
  int b = bh >> 4, h = bh & 15;
  float lg = G.lg2[h];
  int tid = threadIdx.x, w = tid>>6, l = tid&63;
  int lr = l&15, lkg = l>>4;
  const size_t base = (size_t)bh * (N_*64);
  int nl_base = w*16 + lkg*4;
  // Q fragments
  bf16x8 qa[2];
  {
    const u16* qp = qh + base + (size_t)(c*64 + w*16 + lr)*64 + lkg*8;
    qa[0] = ld8(qp);
    qa[1] = ld8(qp + 32);
  }
  // cross: yc = q . (S_hi + S_lo)
  f32x4 yc[4];
  for (int t=0;t<4;++t) yc[t] = (f32x4){0.f,0.f,0.f,0.f};
  {
    const u16* sp = Shi + (size_t)(bh*32 + c)*4096;
    const u16* sq = Slo + (size_t)(bh*32 + c)*4096;
    #pragma unroll
    for (int kk=0;kk<2;++kk)
      #pragma unroll
      for (int t=0;t<4;++t) {
        int off = (t*16 + lr)*64 + kk*32 + lkg*8;
        yc[t] = __builtin_amdgcn_mfma_f32_16x16x32_bf16(qa[kk], ld8(sp + off), yc[t], 0,0,0);
        yc[t] = __builtin_amdgcn_mfma_f32_16x16x32_bf16(qa[kk], ld8(sq + off), yc[t], 0,0,0);
      }
  }
  // local: S_loc = Q K^T (diag tile), masked decay, P in LDS, then P V
  f32x4 sacc[4];
  for (int jt=0;jt<4;++jt) sacc[jt] = (f32x4){0.f,0.f,0.f,0.f};
  #pragma unroll
  for (int jt=0;jt<4;++jt) {
    const u16* kp = kh + base + (size_t)(c*64 + jt*16 + lr)*64 + lkg*8;
    sacc[jt] = __builtin_amdgcn_mfma_f32_16x16x32_bf16(qa[0], ld8(kp),    sacc[jt], 0,0,0);
    sacc[jt] = __builtin_amdgcn_mfma_f32_16x16x32_bf16(qa[1], ld8(kp+32), sacc[jt], 0,0,0);
  }
  #pragma unroll
  for (int jt=0;jt<4;++jt)
    #pragma unroll
    for (int r=0;r<4;++r) {
      int d = (nl_base + r) - (jt*16 + lr);
      float p = (d >= 0) ? sacc[jt][r]*0.125f*exp2f((float)d*lg) : 0.0f;
      pl[w][lkg*4+r][jt*16+lr] = f2bf(p);
    }
  f32x4 yacc[4];
  for (int t=0;t<4;++t) yacc[t] = (f32x4){0.f,0.f,0.f,0.f};
  #pragma unroll
  for (int kk2=0;kk2<2;++kk2) {
    bf16x8 pa = *(bf16x8*)&pl[w][lr][kk2*32 + lkg*8];
    #pragma unroll
    for (int t=0;t<4;++t) {
      bf16x8 vb = ld8(vhT + base + (size_t)(t*16 + lr)*N_ + c*64 + kk2*32 + lkg*8);
      yacc[t] = __builtin_amdgcn_mfma_f32_16x16x32_bf16(pa, vb, yacc[t], 0,0,0);
    }
  }
  float cw[4];
  #pragma unroll
  for (int r=0;r<4;++r) cw[r] = 0.125f * exp2f((float)(nl_base + r) * lg);
  for (int t=0;t<4;++t) {
    #pragma unroll
    for (int r=0;r<4;++r) {
      int n = c*64 + nl_base + r;
      int col = h*64 + t*16 + lr;
      y[((size_t)(b*N_ + n))*D_ + col] = yacc[t][r] + cw[r]*yc[t][r];
    }
  }
}

// ---------- MFMA GEMM (128x64 tile) for final wo projection (mode 0 f32 out) ----------
__global__ __launch_bounds__(256) void k_gemm(const u16* __restrict__ A, const u16* __restrict__ Bt,
                       const float* __restrict__ rowscale, const float* __restrict__ mw, int widx,
                       float* __restrict__ outF, u16* __restrict__ outH, int mode) {
  __shared__ u16 As[128*32];
  __shared__ u16 Bs[64*32];
  int tid = threadIdx.x;
  int m0 = blockIdx.x*128, n0 = blockIdx.y*64;
  int w = tid>>6, l = tid&63;
  int wm = (w>>1)*64, wn = (w&1)*32;
  int lr = l&15, lkg = l>>4;
  f32x4 acc[4][2];
  for (int i=0;i<4;++i) for (int j=0;j<2;++j) acc[i][j] = (f32x4){0.f,0.f,0.f,0.f};
  int c0 = tid, c1 = tid + 256;
  const u16* ga0 = A  + (size_t)(m0 + (c0>>2))*D_ + (c0&3)*8;
  const u16* ga1 = A  + (size_t)(m0 + (c1>>2))*D_ + (c1&3)*8;
  const u16* gb0 = Bt + (size_t)(n0 + (c0>>2))*D_ + (c0&3)*8;
  for (int k0 = 0; k0 < D_; k0 += 32) {
    __syncthreads();
    GLDS(ga0 + k0, &As[w*512]);
    GLDS(ga1 + k0, &As[2048 + w*512]);
    GLDS(gb0 + k0, &Bs[w*512]);
    __syncthreads();
    bf16x8 a[4], b[2];
    for (int i=0;i<4;++i) a[i] = ld8(&As[(wm + i*16 + lr)*32 + lkg*8]);
    for (int j=0;j<2;++j) b[j] = ld8(&Bs[(wn + j*16 + lr)*32 + lkg*8]);
    for (int i=0;i<4;++i)
      for (int j=0;j<2;++j)
        acc[i][j] = __builtin_amdgcn_mfma_f32_16x16x32_bf16(a[i], b[j], acc[i][j], 0, 0, 0);
  }
  float sw = mw[widx];
  for (int i=0;i<4;++i) {
    int rowb = m0 + wm + i*16 + lkg*4;
    for (int j=0;j<2;++j) {
      int col = n0 + wn + j*16 + lr;
      float vv[4];
      #pragma unroll
      for (int r=0;r<4;++r) vv[r] = acc[i][j][r] * rowscale[rowb+r] * sw;
      if (mode == 0) {
        #pragma unroll
        for (int r=0;r<4;++r) outF[(size_t)(rowb+r)*D_ + col] = vv[r];
      } else if (mode == 1) {
        #pragma unroll
        for (int r=0;r<4;++r) outF[(size_t)(rowb+r)*D_ + col] = vv[r] / (1.0f + expf(-vv[r]));
      } else {
        int bb = rowb >> 11, h = col >> 6, e = col & 63;
        #pragma unroll
        for (int r=0;r<4;++r) {
          int n = (rowb+r) & 2047;
          outH[(((size_t)(bb*H_ + h))*N_ + n)*64 + e] = f2bf(vv[r]);
        }
      }
    }
  }
}

// ---------- row LayerNorm(y)*g -> z, plus per-row z sums ----------
__global__ void k_ln_mul(const float* __restrict__ y, const float* __restrict__ g,
                         const float* __restrict__ lnw, const float* __restrict__ lnb,
                         float* __restrict__ z, double* __restrict__ zrow) {
  int m = blockIdx.x, t = threadIdx.x;
  float4 v = *(const float4*)(y + (size_t)m*D_ + t*4);
  double s  = (double)v.x + (double)v.y + (double)v.z + (double)v.w;
  double s2 = (double)v.x*v.x + (double)v.y*v.y + (double)v.z*v.z + (double)v.w*v.w;
  __shared__ double lds[8];
  int w = t>>6, l = t&63;
  for (int o = 32; o > 0; o >>= 1) { s += __shfl_down(s,o); s2 += __shfl_down(s2,o); }
  if (l==0) { lds[w*2]=s; lds[w*2+1]=s2; }
  __syncthreads();
  double ts = lds[0]+lds[2]+lds[4]+lds[6], ts2 = lds[1]+lds[3]+lds[5]+lds[7];
  float mu = (float)(ts/(double)D_);
  float var = (float)(ts2/(double)D_) - mu*mu;
  float rstd = rsqrtf(var + 1e-5f);
  float4 gv = *(const float4*)(g + (size_t)m*D_ + t*4);
  float4 lw = *(const float4*)(lnw + t*4);
  float4 lb = *(const float4*)(lnb + t*4);
  float z0 = ((v.x-mu)*rstd*lw.x + lb.x)*gv.x;
  float z1 = ((v.y-mu)*rstd*lw.y + lb.y)*gv.y;
  float z2 = ((v.z-mu)*rstd*lw.z + lb.z)*gv.z;
  float z3 = ((v.w-mu)*rstd*lw.w + lb.w)*gv.w;
  float4 zo; zo.x=z0; zo.y=z1; zo.z=z2; zo.w=z3;
  *(float4*)(z + (size_t)m*D_ + t*4) = zo;
  double zs  = (double)z0 + (double)z1 + (double)z2 + (double)z3;
  double zs2 = (double)z0*z0 + (double)z1*z1 + (double)z2*z2 + (double)z3*z3;
  for (int o = 32; o > 0; o >>= 1) { zs += __shfl_down(zs,o); zs2 += __shfl_down(zs2,o); }
  __syncthreads();
  if (l==0) { lds[w*2]=zs; lds[w*2+1]=zs2; }
  __syncthreads();
  if (t==0) {
    zrow[m*2]   = lds[0]+lds[2]+lds[4]+lds[6];
    zrow[m*2+1] = lds[1]+lds[3]+lds[5]+lds[7];
  }
}

__global__ void k_zstats_final(const double* __restrict__ zrow, float* __restrict__ stats) {
  int b = blockIdx.x, t = threadIdx.x; // 256
  double s=0.0, s2=0.0;
  for (int k=0;k<8;++k) {
    int m = b*2048 + k*256 + t;
    s += zrow[m*2]; s2 += zrow[m*2+1];
  }
  for (int o = 32; o > 0; o >>= 1) { s += __shfl_down(s,o); s2 += __shfl_down(s2,o); }
  __shared__ double lds[8];
  int w = t>>6, l = t&63;
  if (l==0) { lds[w*2]=s; lds[w*2+1]=s2; }
  __syncthreads();
  if (t==0) {
    double ts = lds[0]+lds[2]+lds[4]+lds[6], ts2 = lds[1]+lds[3]+lds[5]+lds[7];
    double inv = 1.0/(double)(N_*D_);
    double mu = ts*inv, var = ts2*inv - mu*mu;
    stats[b*2]   = (float)mu;
    stats[b*2+1] = rsqrtf((float)var + 1e-5f);
  }
}

extern "C" void kernel_launch(void* const* d_in, const int* in_sizes, int n_in,
                              void* d_out, int out_size, void* d_ws, size_t ws_size,
                              hipStream_t stream) {
  const float* x = (const float*)d_in[0];
  Ptr5 W;
  for (int i = 0; i < 5; ++i) W.p[i] = (const float*)d_in[1+i];
  const float* lnw = (const float*)d_in[6];
  const float* lnb = (const float*)d_in[7];

  char* ws = (char*)d_ws;
  float*  xstats = (float*)(ws + 0);
  float*  zstats = (float*)(ws + 64);
  float*  mw     = (float*)(ws + 128);
  float*  invmw  = (float*)(ws + 192);
  double* part1  = (double*)(ws + 256);      // 128*2 doubles
  double* wpart  = (double*)(ws + 2304);     // 80 doubles
  float*  inv1   = (float*)(ws + 3072);      // 4096
  float*  inv2   = (float*)(ws + 19456);     // 4096
  double* zrow   = (double*)(ws + 35840);    // 4096*2
  u16*    wt     = (u16*)(ws + 101376);      // 5*1M bf16 (10.49 MB)
  u16*    qx     = (u16*)(ws + 10587136);    // 4096x1024 bf16 (8.39 MB)
  u16*    qh     = (u16*)(ws + 18975744);
  u16*    kh     = (u16*)(ws + 27364352);
  u16*    vhT    = (u16*)(ws + 35752960);    // [B,H,64,N]
  float*  gbuf   = (float*)(ws + 44141568);  // f32 16.78 MB
  float*  ybuf   = (float*)(ws + 60918784);  // f32 16.78 MB
  float*  zbuf   = (float*)(ws + 77696000);  // f32 16.78 MB
  // aliases (lifetimes verified against dispatch order):
  float*  Mbuf   = (float*)(ws + 77696000);  // = zbuf region; consumed by scan before ln_mul writes z
  u16*    Shi    = (u16*)(ws + 10587136);    // = qx region; qx dead after fused GEMM, region re-quantized later
  u16*    Slo    = (u16*)(ws + 101376);      // = wt matrices 0-3; dead after fused GEMM; wo weights at +8.39MB untouched
  u16*    qz     = qx;

  GammaArg G;
  {
    double l0 = log(1.0/32.0), l1 = log(1.0/512.0);
    for (int h = 0; h < 16; ++h) {
      float t = (float)(l0 + (l1-l0)*((double)h/15.0));
      float gm = 1.0f - expf(t);
      G.lg2[h] = (float)log2((double)gm);
    }
  }

  dim3 b256(256);
  hipLaunchKernelGGL(k_batch_stats_partial, dim3(64, B_), b256, 0, stream, x, part1);
  hipLaunchKernelGGL(k_batch_stats_final, dim3(B_), dim3(64), 0, stream, part1, xstats);
  hipLaunchKernelGGL(k_wmean_partial, dim3(16, 5), b256, 0, stream, W, wpart);
  hipLaunchKernelGGL(k_wmean_final, dim3(5), dim3(64), 0, stream, wpart, mw, invmw);
  hipLaunchKernelGGL(k_ternarize, dim3(1024, 5), b256, 0, stream, W, invmw, wt);
  hipLaunchKernelGGL(k_quant_rows, dim3(M_), b256, 0, stream, x, xstats, qx, inv1);

  hipLaunchKernelGGL(k_gemm_qkvg, dim3(32, 32), b256, 0, stream, qx, wt, inv1, mw, qh, kh, vhT, gbuf);

  hipLaunchKernelGGL(k_state, dim3(32, 32), b256, 0, stream, kh, vhT, Mbuf, G);
  hipLaunchKernelGGL(k_scan, dim3(16, 32), b256, 0, stream, Mbuf, Shi, Slo, G);
  hipLaunchKernelGGL(k_retB, dim3(32, 32), b256, 0, stream, qh, kh, vhT, Shi, Slo, ybuf, G);

  hipLaunchKernelGGL(k_ln_mul, dim3(M_), b256, 0, stream, ybuf, gbuf, lnw, lnb, zbuf, zrow);
  hipLaunchKernelGGL(k_zstats_final, dim3(B_), b256, 0, stream, zrow, zstats);
  hipLaunchKernelGGL(k_quant_rows, dim3(M_), b256, 0, stream, zbuf, zstats, qz, inv2);
  hipLaunchKernelGGL(k_gemm, dim3(32,16), b256, 0, stream, qz, wt + (size_t)4*1048576, inv2, mw, 4, (float*)d_out, (u16*)nullptr, 0);
}

// Round 6
// 288.212 us; speedup vs baseline: 1.7230x; 1.7230x over previous
//
#include <hip/hip_runtime.h>
#include <math.h>

#define B_ 2
#define N_ 2048
#define D_ 1024
#define H_ 16
#define M_ (B_*N_)

typedef unsigned short u16;
typedef unsigned int u32;
typedef short bf16x8 __attribute__((ext_vector_type(8)));
typedef float f32x4 __attribute__((ext_vector_type(4)));

struct Ptr5 { const float* p[5]; };
struct GammaArg { float lg2[16]; };

static __device__ inline u16 f2bf(float f) {
  union { float f; unsigned u; } x; x.f = f;
  unsigned u = x.u;
  unsigned r = (u + 0x7fffu + ((u >> 16) & 1u)) >> 16;
  return (u16)r;
}
static __device__ inline float bf2f(u16 h) {
  union { unsigned u; float f; } x; x.u = ((unsigned)h) << 16; return x.f;
}
static __device__ inline bf16x8 ld8(const u16* p) {
  uint4 u = *(const uint4*)(p);
  return *reinterpret_cast<bf16x8*>(&u);
}
#define GLDS(g, l) __builtin_amdgcn_global_load_lds((const __attribute__((address_space(1))) u32*)(g), (__attribute__((address_space(3))) u32*)(l), 16, 0, 0)

// ---------- batch stats of x (sum, sumsq) ----------
__global__ void k_batch_stats_partial(const float* __restrict__ x, double* __restrict__ part) {
  int b = blockIdx.y, c = blockIdx.x, t = threadIdx.x;
  const float* p = x + (size_t)b*(N_*D_) + (size_t)c*32768;
  double s = 0.0, s2 = 0.0;
  for (int it = 0; it < 32; ++it) {
    float4 v = *(const float4*)(p + it*1024 + t*4);
    s  += (double)v.x + (double)v.y + (double)v.z + (double)v.w;
    s2 += (double)v.x*v.x + (double)v.y*v.y + (double)v.z*v.z + (double)v.w*v.w;
  }
  for (int o = 32; o > 0; o >>= 1) { s += __shfl_down(s,o); s2 += __shfl_down(s2,o); }
  __shared__ double lds[8];
  int w = t>>6, l = t&63;
  if (l==0) { lds[w*2]=s; lds[w*2+1]=s2; }
  __syncthreads();
  if (t==0) {
    part[(b*64+c)*2]   = lds[0]+lds[2]+lds[4]+lds[6];
    part[(b*64+c)*2+1] = lds[1]+lds[3]+lds[5]+lds[7];
  }
}

__global__ void k_batch_stats_final(const double* __restrict__ part, float* __restrict__ stats) {
  int b = blockIdx.x, t = threadIdx.x; // 64 threads
  double s = part[(b*64+t)*2], s2 = part[(b*64+t)*2+1];
  for (int o = 32; o > 0; o >>= 1) { s += __shfl_down(s,o); s2 += __shfl_down(s2,o); }
  if (t==0) {
    double inv = 1.0/(double)(N_*D_);
    double mu = s*inv, var = s2*inv - mu*mu;
    stats[b*2]   = (float)mu;
    stats[b*2+1] = rsqrtf((float)var + 1e-5f);
  }
}

// ---------- weight abs-mean ----------
__global__ void k_wmean_partial(Ptr5 W, double* __restrict__ part) {
  int wi = blockIdx.y, c = blockIdx.x, t = threadIdx.x;
  const float* p = W.p[wi] + (size_t)c*65536;
  double s = 0.0;
  for (int it = 0; it < 64; ++it) {
    float4 v = *(const float4*)(p + it*1024 + t*4);
    s += fabs((double)v.x)+fabs((double)v.y)+fabs((double)v.z)+fabs((double)v.w);
  }
  for (int o = 32; o > 0; o >>= 1) s += __shfl_down(s,o);
  __shared__ double lds[4];
  if ((t&63)==0) lds[t>>6]=s;
  __syncthreads();
  if (t==0) part[wi*16+c] = lds[0]+lds[1]+lds[2]+lds[3];
}

__global__ void k_wmean_final(const double* __restrict__ part, float* __restrict__ mw, float* __restrict__ invmw) {
  int wi = blockIdx.x, t = threadIdx.x;
  double s = (t<16) ? part[wi*16+t] : 0.0;
  for (int o = 8; o > 0; o >>= 1) s += __shfl_down(s,o);
  if (t==0) {
    double mean = s / (double)(D_*D_);
    float mwc = fmaxf((float)mean, 1e-5f);
    mw[wi] = mwc;
    invmw[wi] = 1.0f/mwc;
  }
}

__global__ void k_ternarize(Ptr5 W, const float* __restrict__ invmw, u16* __restrict__ wt) {
  int wi = blockIdx.y;
  float inv = invmw[wi];
  size_t off = (size_t)blockIdx.x*1024 + threadIdx.x*4;
  float4 v = *(const float4*)(W.p[wi] + off);
  ushort4 o4;
  o4.x = f2bf(fminf(fmaxf(rintf(v.x*inv),-1.f),1.f));
  o4.y = f2bf(fminf(fmaxf(rintf(v.y*inv),-1.f),1.f));
  o4.z = f2bf(fminf(fmaxf(rintf(v.z*inv),-1.f),1.f));
  o4.w = f2bf(fminf(fmaxf(rintf(v.w*inv),-1.f),1.f));
  *(ushort4*)(wt + (size_t)wi*(D_*D_) + off) = o4;
}

// ---------- per-row activation quant (shared LN stats) ----------
__global__ void k_quant_rows(const float* __restrict__ in, const float* __restrict__ stats,
                             u16* __restrict__ q, float* __restrict__ rowscale) {
  int m = blockIdx.x, t = threadIdx.x;
  int b = m >> 11;
  float mu = stats[b*2], rstd = stats[b*2+1];
  float4 v = *(const float4*)(in + (size_t)m*D_ + t*4);
  float xn0 = (v.x-mu)*rstd, xn1 = (v.y-mu)*rstd, xn2 = (v.z-mu)*rstd, xn3 = (v.w-mu)*rstd;
  float am = fmaxf(fmaxf(fabsf(xn0),fabsf(xn1)),fmaxf(fabsf(xn2),fabsf(xn3)));
  for (int o = 32; o > 0; o >>= 1) am = fmaxf(am, __shfl_xor(am,o));
  __shared__ float wm[4];
  int w = t>>6, l = t&63;
  if (l==0) wm[w]=am;
  __syncthreads();
  am = fmaxf(fmaxf(wm[0],wm[1]),fmaxf(wm[2],wm[3]));
  float clipped = fmaxf(am, 1e-5f);
  float sc = 127.0f/clipped;
  ushort4 o4;
  o4.x = f2bf(fminf(fmaxf(rintf(xn0*sc),-128.f),127.f));
  o4.y = f2bf(fminf(fmaxf(rintf(xn1*sc),-128.f),127.f));
  o4.z = f2bf(fminf(fmaxf(rintf(xn2*sc),-128.f),127.f));
  o4.w = f2bf(fminf(fmaxf(rintf(xn3*sc),-128.f),127.f));
  *(ushort4*)(q + (size_t)m*D_ + t*4) = o4;
  if (t==0) rowscale[m] = clipped/127.0f;
}

// ---------- fused q/k/v/g GEMM: 128x128 tile, BK=32, LDS-restaged dense epilogue ----------
// Wt = 4 concatenated [1024,1024] ternary matrices -> [4096,1024].
// widx 0: qh [B,H,N,64]; 1: kh [B,H,N,64]; 2: vhT [B,H,64,N]; 3: silu -> gbufH bf16 [M,D].
__global__ __launch_bounds__(256) void k_gemm_qkvg(const u16* __restrict__ A, const u16* __restrict__ Wt,
                       const float* __restrict__ rowscale, const float* __restrict__ mw,
                       u16* __restrict__ qh, u16* __restrict__ kh, u16* __restrict__ vhT,
                       u16* __restrict__ gbufH) {
  __shared__ u16 smem[8192];   // As = smem[0..4095], Bs = smem[4096..8191]; epilogue stage [32][136]
  int tid = threadIdx.x;
  int m0 = blockIdx.x*128, n0g = blockIdx.y*128;
  int widx = blockIdx.y >> 3;
  int w = tid>>6, l = tid&63;
  int wm = (w>>1)*64, wn = (w&1)*64;
  int lr = l&15, lkg = l>>4;
  f32x4 acc[4][4];
  for (int i=0;i<4;++i) for (int j=0;j<4;++j) acc[i][j] = (f32x4){0.f,0.f,0.f,0.f};
  int c0 = tid, c1 = tid + 256;
  const u16* ga0 = A  + (size_t)(m0 + (c0>>2))*D_ + (c0&3)*8;
  const u16* ga1 = A  + (size_t)(m0 + (c1>>2))*D_ + (c1&3)*8;
  const u16* gb0 = Wt + (size_t)(n0g + (c0>>2))*D_ + (c0&3)*8;
  const u16* gb1 = Wt + (size_t)(n0g + (c1>>2))*D_ + (c1&3)*8;
  for (int k0 = 0; k0 < D_; k0 += 32) {
    __syncthreads();
    GLDS(ga0 + k0, &smem[w*512]);
    GLDS(ga1 + k0, &smem[2048 + w*512]);
    GLDS(gb0 + k0, &smem[4096 + w*512]);
    GLDS(gb1 + k0, &smem[6144 + w*512]);
    __syncthreads();
    bf16x8 a[4], b[4];
    #pragma unroll
    for (int i=0;i<4;++i) a[i] = ld8(&smem[(wm + i*16 + lr)*32 + lkg*8]);
    #pragma unroll
    for (int j=0;j<4;++j) b[j] = ld8(&smem[4096 + (wn + j*16 + lr)*32 + lkg*8]);
    #pragma unroll
    for (int i=0;i<4;++i)
      #pragma unroll
      for (int j=0;j<4;++j)
        acc[i][j] = __builtin_amdgcn_mfma_f32_16x16x32_bf16(a[i], b[j], acc[i][j], 0, 0, 0);
  }
  // ---- epilogue: LDS restage -> dense 16B coalesced stores ----
  float sw = mw[widx];
  int bb0 = m0 >> 11;
  int h0 = (n0g >> 6) & 15;
  #pragma unroll
  for (int g = 0; g < 4; ++g) {
    __syncthreads();
    if (widx != 2) {
      // row-major staging: phase g = tile rows 32g..32g+31
      if ((w>>1) == (g>>1)) {
        #pragma unroll
        for (int ii = 0; ii < 2; ++ii) {
          int i = (g&1)*2 + ii;
          #pragma unroll
          for (int j = 0; j < 4; ++j) {
            int col = wn + j*16 + lr;
            #pragma unroll
            for (int r = 0; r < 4; ++r) {
              int rloc = ii*16 + lkg*4 + r;
              int row = m0 + g*32 + rloc;
              float v = acc[i][j][r] * rowscale[row] * sw;
              if (widx == 3) v = v / (1.0f + __expf(-v));
              smem[rloc*136 + col] = f2bf(v);
            }
          }
        }
      }
    } else {
      // col-major staging: phase g = tile cols 32g..32g+31, stage[colrel][row]
      if ((w&1) == (g>>1)) {
        #pragma unroll
        for (int jj = 0; jj < 2; ++jj) {
          int j = (g&1)*2 + jj;
          #pragma unroll
          for (int i = 0; i < 4; ++i) {
            #pragma unroll
            for (int r = 0; r < 4; ++r) {
              int rowrel = wm + i*16 + lkg*4 + r;
              float v = acc[i][j][r] * rowscale[m0 + rowrel] * sw;
              smem[(jj*16 + lr)*136 + rowrel] = f2bf(v);
            }
          }
        }
      }
    }
    __syncthreads();
    #pragma unroll
    for (int u = 0; u < 2; ++u) {
      int c = u*256 + tid;
      int rr = c >> 4, k8 = c & 15;
      uint4 val = *(const uint4*)&smem[rr*136 + k8*8];
      if (widx <= 1) {
        int row = m0 + g*32 + rr;
        int n = row & 2047;
        int h = h0 + (k8 >> 3);
        int e8 = (k8 & 7)*8;
        u16* dst = widx ? kh : qh;
        *(uint4*)&dst[(((size_t)((row>>11)*H_ + h))*N_ + n)*64 + e8] = val;
      } else if (widx == 2) {
        int ecol = n0g + g*32 + rr;
        int h = (ecol >> 6) & 15, e = ecol & 63;
        int n8 = (m0 & 2047) + k8*8;
        *(uint4*)&vhT[(((size_t)(bb0*H_ + h))*64 + e)*N_ + n8] = val;
      } else {
        int row = m0 + g*32 + rr;
        int d = (n0g & 1023) + k8*8;
        *(uint4*)&gbufH[(size_t)row*D_ + d] = val;
      }
    }
  }
}

// ---------- retention phase A: per-chunk state contribution ----------
// M_c[dv][dk] = sum_j gamma^(64-j) * v[c*64+j][dv] * k[c*64+j][dk]   (f32)
__global__ __launch_bounds__(256) void k_state(const u16* __restrict__ kh, const u16* __restrict__ vhT,
                       float* __restrict__ Mbuf, GammaArg G) {
  __shared__ u16 kT[64][72];   // [dk][j]
  int c = blockIdx.x, bh = blockIdx.y;
  float lg = G.lg2[bh & 15];
  int tid = threadIdx.x, w = tid>>6, l = tid&63;
  int lr = l&15, lkg = l>>4;
  const size_t base = (size_t)bh * (N_*64);
  // stage K^T (transpose via LDS)
  {
    int j = tid>>2, cs = (tid&3)*16;
    const u16* kp = kh + base + (size_t)(c*64 + j)*64 + cs;
    uint4 u0 = *(const uint4*)kp;
    uint4 u1 = *(const uint4*)(kp + 8);
    const u16* s0 = (const u16*)&u0;
    const u16* s1 = (const u16*)&u1;
    #pragma unroll
    for (int m2=0;m2<8;++m2) kT[cs+m2][j] = s0[m2];
    #pragma unroll
    for (int m2=0;m2<8;++m2) kT[cs+8+m2][j] = s1[m2];
  }
  __syncthreads();
  // weighted V^T fragments, hi/lo bf16 split
  bf16x8 ah[2], al[2];
  #pragma unroll
  for (int kk=0;kk<2;++kk) {
    bf16x8 raw = ld8(vhT + base + (size_t)(w*16 + lr)*N_ + c*64 + kk*32 + lkg*8);
    #pragma unroll
    for (int m2=0;m2<8;++m2) {
      int j = kk*32 + lkg*8 + m2;
      float wj = exp2f((float)(64 - j) * lg);
      float p = bf2f((u16)raw[m2]) * wj;
      u16 hh = f2bf(p);
      ah[kk][m2] = (short)hh;
      al[kk][m2] = (short)f2bf(p - bf2f(hh));
    }
  }
  f32x4 macc[4];
  for (int t=0;t<4;++t) macc[t] = (f32x4){0.f,0.f,0.f,0.f};
  #pragma unroll
  for (int t=0;t<4;++t)
    #pragma unroll
    for (int kk=0;kk<2;++kk) {
      bf16x8 b = ld8(&kT[t*16 + lr][kk*32 + lkg*8]);
      macc[t] = __builtin_amdgcn_mfma_f32_16x16x32_bf16(ah[kk], b, macc[t], 0,0,0);
      macc[t] = __builtin_amdgcn_mfma_f32_16x16x32_bf16(al[kk], b, macc[t], 0,0,0);
    }
  float* mp = Mbuf + (size_t)(bh*32 + c)*4096;
  for (int t=0;t<4;++t) {
    #pragma unroll
    for (int r=0;r<4;++r)
      mp[(w*16 + lkg*4 + r)*64 + t*16 + lr] = macc[t][r];
  }
}

// ---------- retention scan: S_c = g64*S_{c-1} + M_{c-1}, store bf16 hi/lo ----------
__global__ void k_scan(const float* __restrict__ Mbuf, u16* __restrict__ Shi, u16* __restrict__ Slo, GammaArg G) {
  int bx = blockIdx.x, bh = blockIdx.y;
  float g64 = exp2f(64.0f * G.lg2[bh & 15]);
  int e = bx*256 + threadIdx.x;
  size_t eb = (size_t)bh*32*4096 + e;
  float S = 0.0f;
  Shi[eb] = 0; Slo[eb] = 0;
  #pragma unroll
  for (int c = 1; c < 32; ++c) {
    S = g64*S + Mbuf[eb + (size_t)(c-1)*4096];
    u16 hh = f2bf(S);
    Shi[eb + (size_t)c*4096] = hh;
    Slo[eb + (size_t)c*4096] = f2bf(S - bf2f(hh));
  }
}

// ---------- retention phase B: y = gamma^i * q . S  +  local (masked decay) ----------
__global__ __launch_bounds__(256) void k_retB(const u16* __restrict__ qh, const u16* __restrict__ kh,
                       const u16* __restrict__ vhT, const u16* __restrict__ Shi, const u16* __restrict__ Slo,
                       float* __restrict__ y, GammaArg G) {
  __shared__ u16 pl[4][16][76];
  int c = blockIdx.x, bh = blockIdx.y;
  int b = bh >> 4, h = bh & 15;
  float lg = G.lg2[h];
  int tid = threadIdx.x, w = tid>>6, l = tid&63;
  int lr = l&15, lkg = l>>4;
  const size_t base = (size_t)bh * (N_*64);
  int nl_base = w*16 + lkg*4;
  // Q fragments
  bf16x8 qa[2];
  {
    const u16* qp = qh + base + (size_t)(c*64 + w*16 + lr)*64 + lkg*8;
    qa[0] = ld8(qp);
    qa[1] = ld8(qp + 32);
  }
  // cross: yc = q . (S_hi + S_lo)
  f32x4 yc[4];
  for (int t=0;t<4;++t) yc[t] = (f32x4){0.f,0.f,0.f,0.f};
  {
    const u16* sp = Shi + (size_t)(bh*32 + c)*4096;
    const u16* sq = Slo + (size_t)(bh*32 + c)*4096;
    #pragma unroll
    for (int kk=0;kk<2;++kk)
      #pragma unroll
      for (int t=0;t<4;++t) {
        int off = (t*16 + lr)*64 + kk*32 + lkg*8;
        yc[t] = __builtin_amdgcn_mfma_f32_16x16x32_bf16(qa[kk], ld8(sp + off), yc[t], 0,0,0);
        yc[t] = __builtin_amdgcn_mfma_f32_16x16x32_bf16(qa[kk], ld8(sq + off), yc[t], 0,0,0);
      }
  }
  // local: S_loc = Q K^T (diag tile), masked decay, P in LDS, then P V
  f32x4 sacc[4];
  for (int jt=0;jt<4;++jt) sacc[jt] = (f32x4){0.f,0.f,0.f,0.f};
  #pragma unroll
  for (int jt=0;jt<4;++jt) {
    const u16* kp = kh + base + (size_t)(c*64 + jt*16 + lr)*64 + lkg*8;
    sacc[jt] = __builtin_amdgcn_mfma_f32_16x16x32_bf16(qa[0], ld8(kp),    sacc[jt], 0,0,0);
    sacc[jt] = __builtin_amdgcn_mfma_f32_16x16x32_bf16(qa[1], ld8(kp+32), sacc[jt], 0,0,0);
  }
  #pragma unroll
  for (int jt=0;jt<4;++jt)
    #pragma unroll
    for (int r=0;r<4;++r) {
      int d = (nl_base + r) - (jt*16 + lr);
      float p = (d >= 0) ? sacc[jt][r]*0.125f*exp2f((float)d*lg) : 0.0f;
      pl[w][lkg*4+r][jt*16+lr] = f2bf(p);
    }
  f32x4 yacc[4];
  for (int t=0;t<4;++t) yacc[t] = (f32x4){0.f,0.f,0.f,0.f};
  #pragma unroll
  for (int kk2=0;kk2<2;++kk2) {
    bf16x8 pa = *(bf16x8*)&pl[w][lr][kk2*32 + lkg*8];
    #pragma unroll
    for (int t=0;t<4;++t) {
      bf16x8 vb = ld8(vhT + base + (size_t)(t*16 + lr)*N_ + c*64 + kk2*32 + lkg*8);
      yacc[t] = __builtin_amdgcn_mfma_f32_16x16x32_bf16(pa, vb, yacc[t], 0,0,0);
    }
  }
  float cw[4];
  #pragma unroll
  for (int r=0;r<4;++r) cw[r] = 0.125f * exp2f((float)(nl_base + r) * lg);
  for (int t=0;t<4;++t) {
    #pragma unroll
    for (int r=0;r<4;++r) {
      int n = c*64 + nl_base + r;
      int col = h*64 + t*16 + lr;
      y[((size_t)(b*N_ + n))*D_ + col] = yacc[t][r] + cw[r]*yc[t][r];
    }
  }
}

// ---------- MFMA GEMM (128x64 tile) for final wo projection (f32 out) ----------
__global__ __launch_bounds__(256) void k_gemm(const u16* __restrict__ A, const u16* __restrict__ Bt,
                       const float* __restrict__ rowscale, const float* __restrict__ mw, int widx,
                       float* __restrict__ outF) {
  __shared__ u16 As[128*32];
  __shared__ u16 Bs[64*32];
  int tid = threadIdx.x;
  int m0 = blockIdx.x*128, n0 = blockIdx.y*64;
  int w = tid>>6, l = tid&63;
  int wm = (w>>1)*64, wn = (w&1)*32;
  int lr = l&15, lkg = l>>4;
  f32x4 acc[4][2];
  for (int i=0;i<4;++i) for (int j=0;j<2;++j) acc[i][j] = (f32x4){0.f,0.f,0.f,0.f};
  int c0 = tid, c1 = tid + 256;
  const u16* ga0 = A  + (size_t)(m0 + (c0>>2))*D_ + (c0&3)*8;
  const u16* ga1 = A  + (size_t)(m0 + (c1>>2))*D_ + (c1&3)*8;
  const u16* gb0 = Bt + (size_t)(n0 + (c0>>2))*D_ + (c0&3)*8;
  for (int k0 = 0; k0 < D_; k0 += 32) {
    __syncthreads();
    GLDS(ga0 + k0, &As[w*512]);
    GLDS(ga1 + k0, &As[2048 + w*512]);
    GLDS(gb0 + k0, &Bs[w*512]);
    __syncthreads();
    bf16x8 a[4], b[2];
    for (int i=0;i<4;++i) a[i] = ld8(&As[(wm + i*16 + lr)*32 + lkg*8]);
    for (int j=0;j<2;++j) b[j] = ld8(&Bs[(wn + j*16 + lr)*32 + lkg*8]);
    for (int i=0;i<4;++i)
      for (int j=0;j<2;++j)
        acc[i][j] = __builtin_amdgcn_mfma_f32_16x16x32_bf16(a[i], b[j], acc[i][j], 0, 0, 0);
  }
  float sw = mw[widx];
  for (int i=0;i<4;++i) {
    int rowb = m0 + wm + i*16 + lkg*4;
    for (int j=0;j<2;++j) {
      int col = n0 + wn + j*16 + lr;
      #pragma unroll
      for (int r=0;r<4;++r)
        outF[(size_t)(rowb+r)*D_ + col] = acc[i][j][r] * rowscale[rowb+r] * sw;
    }
  }
}

// ---------- row LayerNorm(y)*g -> z, plus per-row z sums (g is bf16) ----------
__global__ void k_ln_mul(const float* __restrict__ y, const u16* __restrict__ gH,
                         const float* __restrict__ lnw, const float* __restrict__ lnb,
                         float* __restrict__ z, double* __restrict__ zrow) {
  int m = blockIdx.x, t = threadIdx.x;
  float4 v = *(const float4*)(y + (size_t)m*D_ + t*4);
  double s  = (double)v.x + (double)v.y + (double)v.z + (double)v.w;
  double s2 = (double)v.x*v.x + (double)v.y*v.y + (double)v.z*v.z + (double)v.w*v.w;
  __shared__ double lds[8];
  int w = t>>6, l = t&63;
  for (int o = 32; o > 0; o >>= 1) { s += __shfl_down(s,o); s2 += __shfl_down(s2,o); }
  if (l==0) { lds[w*2]=s; lds[w*2+1]=s2; }
  __syncthreads();
  double ts = lds[0]+lds[2]+lds[4]+lds[6], ts2 = lds[1]+lds[3]+lds[5]+lds[7];
  float mu = (float)(ts/(double)D_);
  float var = (float)(ts2/(double)D_) - mu*mu;
  float rstd = rsqrtf(var + 1e-5f);
  ushort4 gv4 = *(const ushort4*)(gH + (size_t)m*D_ + t*4);
  float g0 = bf2f(gv4.x), g1 = bf2f(gv4.y), g2 = bf2f(gv4.z), g3 = bf2f(gv4.w);
  float4 lw = *(const float4*)(lnw + t*4);
  float4 lb = *(const float4*)(lnb + t*4);
  float z0 = ((v.x-mu)*rstd*lw.x + lb.x)*g0;
  float z1 = ((v.y-mu)*rstd*lw.y + lb.y)*g1;
  float z2 = ((v.z-mu)*rstd*lw.z + lb.z)*g2;
  float z3 = ((v.w-mu)*rstd*lw.w + lb.w)*g3;
  float4 zo; zo.x=z0; zo.y=z1; zo.z=z2; zo.w=z3;
  *(float4*)(z + (size_t)m*D_ + t*4) = zo;
  double zs  = (double)z0 + (double)z1 + (double)z2 + (double)z3;
  double zs2 = (double)z0*z0 + (double)z1*z1 + (double)z2*z2 + (double)z3*z3;
  for (int o = 32; o > 0; o >>= 1) { zs += __shfl_down(zs,o); zs2 += __shfl_down(zs2,o); }
  __syncthreads();
  if (l==0) { lds[w*2]=zs; lds[w*2+1]=zs2; }
  __syncthreads();
  if (t==0) {
    zrow[m*2]   = lds[0]+lds[2]+lds[4]+lds[6];
    zrow[m*2+1] = lds[1]+lds[3]+lds[5]+lds[7];
  }
}

__global__ void k_zstats_final(const double* __restrict__ zrow, float* __restrict__ stats) {
  int b = blockIdx.x, t = threadIdx.x; // 256
  double s=0.0, s2=0.0;
  for (int k=0;k<8;++k) {
    int m = b*2048 + k*256 + t;
    s += zrow[m*2]; s2 += zrow[m*2+1];
  }
  for (int o = 32; o > 0; o >>= 1) { s += __shfl_down(s,o); s2 += __shfl_down(s2,o); }
  __shared__ double lds[8];
  int w = t>>6, l = t&63;
  if (l==0) { lds[w*2]=s; lds[w*2+1]=s2; }
  __syncthreads();
  if (t==0) {
    double ts = lds[0]+lds[2]+lds[4]+lds[6], ts2 = lds[1]+lds[3]+lds[5]+lds[7];
    double inv = 1.0/(double)(N_*D_);
    double mu = ts*inv, var = ts2*inv - mu*mu;
    stats[b*2]   = (float)mu;
    stats[b*2+1] = rsqrtf((float)var + 1e-5f);
  }
}

extern "C" void kernel_launch(void* const* d_in, const int* in_sizes, int n_in,
                              void* d_out, int out_size, void* d_ws, size_t ws_size,
                              hipStream_t stream) {
  const float* x = (const float*)d_in[0];
  Ptr5 W;
  for (int i = 0; i < 5; ++i) W.p[i] = (const float*)d_in[1+i];
  const float* lnw = (const float*)d_in[6];
  const float* lnb = (const float*)d_in[7];

  char* ws = (char*)d_ws;
  float*  xstats = (float*)(ws + 0);
  float*  zstats = (float*)(ws + 64);
  float*  mw     = (float*)(ws + 128);
  float*  invmw  = (float*)(ws + 192);
  double* part1  = (double*)(ws + 256);      // 128*2 doubles
  double* wpart  = (double*)(ws + 2304);     // 80 doubles
  float*  inv1   = (float*)(ws + 3072);      // 4096
  float*  inv2   = (float*)(ws + 19456);     // 4096
  double* zrow   = (double*)(ws + 35840);    // 4096*2
  u16*    wt     = (u16*)(ws + 101376);      // 5*1M bf16 (10.49 MB)
  u16*    qx     = (u16*)(ws + 10587136);    // 4096x1024 bf16 (8.39 MB)
  u16*    qh     = (u16*)(ws + 18975744);
  u16*    kh     = (u16*)(ws + 27364352);
  u16*    vhT    = (u16*)(ws + 35752960);    // [B,H,64,N]
  u16*    gbufH  = (u16*)(ws + 44141568);    // bf16 [M,D] 8.39 MB
  float*  ybuf   = (float*)(ws + 60918784);  // f32 16.78 MB
  float*  zbuf   = (float*)(ws + 77696000);  // f32 16.78 MB
  // aliases (lifetimes verified against dispatch order):
  float*  Mbuf   = (float*)(ws + 77696000);  // = zbuf region; consumed by scan before ln_mul writes z
  u16*    Shi    = (u16*)(ws + 10587136);    // = qx region; qx dead after fused GEMM
  u16*    Slo    = (u16*)(ws + 101376);      // = wt matrices 0-3; dead after fused GEMM; wo weights untouched
  u16*    qz     = qx;

  GammaArg G;
  {
    double l0 = log(1.0/32.0), l1 = log(1.0/512.0);
    for (int h = 0; h < 16; ++h) {
      float t = (float)(l0 + (l1-l0)*((double)h/15.0));
      float gm = 1.0f - expf(t);
      G.lg2[h] = (float)log2((double)gm);
    }
  }

  dim3 b256(256);
  hipLaunchKernelGGL(k_batch_stats_partial, dim3(64, B_), b256, 0, stream, x, part1);
  hipLaunchKernelGGL(k_batch_stats_final, dim3(B_), dim3(64), 0, stream, part1, xstats);
  hipLaunchKernelGGL(k_wmean_partial, dim3(16, 5), b256, 0, stream, W, wpart);
  hipLaunchKernelGGL(k_wmean_final, dim3(5), dim3(64), 0, stream, wpart, mw, invmw);
  hipLaunchKernelGGL(k_ternarize, dim3(1024, 5), b256, 0, stream, W, invmw, wt);
  hipLaunchKernelGGL(k_quant_rows, dim3(M_), b256, 0, stream, x, xstats, qx, inv1);

  hipLaunchKernelGGL(k_gemm_qkvg, dim3(32, 32), b256, 0, stream, qx, wt, inv1, mw, qh, kh, vhT, gbufH);

  hipLaunchKernelGGL(k_state, dim3(32, 32), b256, 0, stream, kh, vhT, Mbuf, G);
  hipLaunchKernelGGL(k_scan, dim3(16, 32), b256, 0, stream, Mbuf, Shi, Slo, G);
  hipLaunchKernelGGL(k_retB, dim3(32, 32), b256, 0, stream, qh, kh, vhT, Shi, Slo, ybuf, G);

  hipLaunchKernelGGL(k_ln_mul, dim3(M_), b256, 0, stream, ybuf, gbufH, lnw, lnb, zbuf, zrow);
  hipLaunchKernelGGL(k_zstats_final, dim3(B_), b256, 0, stream, zrow, zstats);
  hipLaunchKernelGGL(k_quant_rows, dim3(M_), b256, 0, stream, zbuf, zstats, qz, inv2);
  hipLaunchKernelGGL(k_gemm, dim3(32,16), b256, 0, stream, qz, wt + (size_t)4*1048576, inv2, mw, 4, (float*)d_out);
}

// Round 7
// 238.426 us; speedup vs baseline: 2.0828x; 1.2088x over previous
//
#include <hip/hip_runtime.h>
#include <math.h>

#define B_ 2
#define N_ 2048
#define D_ 1024
#define H_ 16
#define M_ (B_*N_)

typedef unsigned short u16;
typedef unsigned int u32;
typedef short bf16x8 __attribute__((ext_vector_type(8)));
typedef float f32x4 __attribute__((ext_vector_type(4)));

struct Ptr5 { const float* p[5]; };
struct GammaArg { float lg2[16]; };

static __device__ inline u16 f2bf(float f) {
  union { float f; unsigned u; } x; x.f = f;
  unsigned u = x.u;
  unsigned r = (u + 0x7fffu + ((u >> 16) & 1u)) >> 16;
  return (u16)r;
}
static __device__ inline float bf2f(u16 h) {
  union { unsigned u; float f; } x; x.u = ((unsigned)h) << 16; return x.f;
}
static __device__ inline bf16x8 ld8(const u16* p) {
  uint4 u = *(const uint4*)(p);
  return *reinterpret_cast<bf16x8*>(&u);
}
#define GLDS(g, l) __builtin_amdgcn_global_load_lds((const __attribute__((address_space(1))) u32*)(g), (__attribute__((address_space(3))) u32*)(l), 16, 0, 0)

// ---------- batch stats of x (sum, sumsq) ----------
__global__ void k_batch_stats_partial(const float* __restrict__ x, double* __restrict__ part) {
  int b = blockIdx.y, c = blockIdx.x, t = threadIdx.x;
  const float* p = x + (size_t)b*(N_*D_) + (size_t)c*32768;
  double s = 0.0, s2 = 0.0;
  for (int it = 0; it < 32; ++it) {
    float4 v = *(const float4*)(p + it*1024 + t*4);
    s  += (double)v.x + (double)v.y + (double)v.z + (double)v.w;
    s2 += (double)v.x*v.x + (double)v.y*v.y + (double)v.z*v.z + (double)v.w*v.w;
  }
  for (int o = 32; o > 0; o >>= 1) { s += __shfl_down(s,o); s2 += __shfl_down(s2,o); }
  __shared__ double lds[8];
  int w = t>>6, l = t&63;
  if (l==0) { lds[w*2]=s; lds[w*2+1]=s2; }
  __syncthreads();
  if (t==0) {
    part[(b*64+c)*2]   = lds[0]+lds[2]+lds[4]+lds[6];
    part[(b*64+c)*2+1] = lds[1]+lds[3]+lds[5]+lds[7];
  }
}

__global__ void k_batch_stats_final(const double* __restrict__ part, float* __restrict__ stats) {
  int b = blockIdx.x, t = threadIdx.x; // 64 threads
  double s = part[(b*64+t)*2], s2 = part[(b*64+t)*2+1];
  for (int o = 32; o > 0; o >>= 1) { s += __shfl_down(s,o); s2 += __shfl_down(s2,o); }
  if (t==0) {
    double inv = 1.0/(double)(N_*D_);
    double mu = s*inv, var = s2*inv - mu*mu;
    stats[b*2]   = (float)mu;
    stats[b*2+1] = rsqrtf((float)var + 1e-5f);
  }
}

// ---------- weight abs-mean ----------
__global__ void k_wmean_partial(Ptr5 W, double* __restrict__ part) {
  int wi = blockIdx.y, c = blockIdx.x, t = threadIdx.x;
  const float* p = W.p[wi] + (size_t)c*65536;
  double s = 0.0;
  for (int it = 0; it < 64; ++it) {
    float4 v = *(const float4*)(p + it*1024 + t*4);
    s += fabs((double)v.x)+fabs((double)v.y)+fabs((double)v.z)+fabs((double)v.w);
  }
  for (int o = 32; o > 0; o >>= 1) s += __shfl_down(s,o);
  __shared__ double lds[4];
  if ((t&63)==0) lds[t>>6]=s;
  __syncthreads();
  if (t==0) part[wi*16+c] = lds[0]+lds[1]+lds[2]+lds[3];
}

__global__ void k_wmean_final(const double* __restrict__ part, float* __restrict__ mw, float* __restrict__ invmw) {
  int wi = blockIdx.x, t = threadIdx.x;
  double s = (t<16) ? part[wi*16+t] : 0.0;
  for (int o = 8; o > 0; o >>= 1) s += __shfl_down(s,o);
  if (t==0) {
    double mean = s / (double)(D_*D_);
    float mwc = fmaxf((float)mean, 1e-5f);
    mw[wi] = mwc;
    invmw[wi] = 1.0f/mwc;
  }
}

__global__ void k_ternarize(Ptr5 W, const float* __restrict__ invmw, u16* __restrict__ wt) {
  int wi = blockIdx.y;
  float inv = invmw[wi];
  size_t off = (size_t)blockIdx.x*1024 + threadIdx.x*4;
  float4 v = *(const float4*)(W.p[wi] + off);
  ushort4 o4;
  o4.x = f2bf(fminf(fmaxf(rintf(v.x*inv),-1.f),1.f));
  o4.y = f2bf(fminf(fmaxf(rintf(v.y*inv),-1.f),1.f));
  o4.z = f2bf(fminf(fmaxf(rintf(v.z*inv),-1.f),1.f));
  o4.w = f2bf(fminf(fmaxf(rintf(v.w*inv),-1.f),1.f));
  *(ushort4*)(wt + (size_t)wi*(D_*D_) + off) = o4;
}

// ---------- per-row activation quant (shared LN stats) ----------
__global__ void k_quant_rows(const float* __restrict__ in, const float* __restrict__ stats,
                             u16* __restrict__ q, float* __restrict__ rowscale) {
  int m = blockIdx.x, t = threadIdx.x;
  int b = m >> 11;
  float mu = stats[b*2], rstd = stats[b*2+1];
  float4 v = *(const float4*)(in + (size_t)m*D_ + t*4);
  float xn0 = (v.x-mu)*rstd, xn1 = (v.y-mu)*rstd, xn2 = (v.z-mu)*rstd, xn3 = (v.w-mu)*rstd;
  float am = fmaxf(fmaxf(fabsf(xn0),fabsf(xn1)),fmaxf(fabsf(xn2),fabsf(xn3)));
  for (int o = 32; o > 0; o >>= 1) am = fmaxf(am, __shfl_xor(am,o));
  __shared__ float wm[4];
  int w = t>>6, l = t&63;
  if (l==0) wm[w]=am;
  __syncthreads();
  am = fmaxf(fmaxf(wm[0],wm[1]),fmaxf(wm[2],wm[3]));
  float clipped = fmaxf(am, 1e-5f);
  float sc = 127.0f/clipped;
  ushort4 o4;
  o4.x = f2bf(fminf(fmaxf(rintf(xn0*sc),-128.f),127.f));
  o4.y = f2bf(fminf(fmaxf(rintf(xn1*sc),-128.f),127.f));
  o4.z = f2bf(fminf(fmaxf(rintf(xn2*sc),-128.f),127.f));
  o4.w = f2bf(fminf(fmaxf(rintf(xn3*sc),-128.f),127.f));
  *(ushort4*)(q + (size_t)m*D_ + t*4) = o4;
  if (t==0) rowscale[m] = clipped/127.0f;
}

// ---------- fused q/k/v/g GEMM: 128x128 tile, BK=32, LDS-restaged dense epilogue ----------
// Wt = 4 concatenated [1024,1024] ternary matrices -> [4096,1024].
// widx 0: qh [B,H,N,64]; 1: kh [B,H,N,64]; 2: vhT [B,H,64,N]; 3: silu -> gbufH bf16 [M,D].
__global__ __launch_bounds__(256, 4) void k_gemm_qkvg(const u16* __restrict__ A, const u16* __restrict__ Wt,
                       const float* __restrict__ rowscale, const float* __restrict__ mw,
                       u16* __restrict__ qh, u16* __restrict__ kh, u16* __restrict__ vhT,
                       u16* __restrict__ gbufH) {
  __shared__ u16 smem[8192];   // As = smem[0..4095], Bs = smem[4096..8191]; epilogue stage [32][136]
  int tid = threadIdx.x;
  // XCD-chunked bijective swizzle: 1024 blocks, 8 XCDs, 128 per XCD.
  // Within an XCD, 32 consecutive blocks share one N-panel (weight panel L2-resident).
  int flat = blockIdx.y * gridDim.x + blockIdx.x;
  int swz = (flat & 7) * 128 + (flat >> 3);
  int mxi = swz & 31, nyi = swz >> 5;
  int m0 = mxi*128, n0g = nyi*128;
  int widx = nyi >> 3;
  int w = tid>>6, l = tid&63;
  int wm = (w>>1)*64, wn = (w&1)*64;
  int lr = l&15, lkg = l>>4;
  f32x4 acc[4][4];
  for (int i=0;i<4;++i) for (int j=0;j<4;++j) acc[i][j] = (f32x4){0.f,0.f,0.f,0.f};
  int c0 = tid, c1 = tid + 256;
  const u16* ga0 = A  + (size_t)(m0 + (c0>>2))*D_ + (c0&3)*8;
  const u16* ga1 = A  + (size_t)(m0 + (c1>>2))*D_ + (c1&3)*8;
  const u16* gb0 = Wt + (size_t)(n0g + (c0>>2))*D_ + (c0&3)*8;
  const u16* gb1 = Wt + (size_t)(n0g + (c1>>2))*D_ + (c1&3)*8;
  for (int k0 = 0; k0 < D_; k0 += 32) {
    __syncthreads();
    GLDS(ga0 + k0, &smem[w*512]);
    GLDS(ga1 + k0, &smem[2048 + w*512]);
    GLDS(gb0 + k0, &smem[4096 + w*512]);
    GLDS(gb1 + k0, &smem[6144 + w*512]);
    __syncthreads();
    bf16x8 a[4], b[4];
    #pragma unroll
    for (int i=0;i<4;++i) a[i] = ld8(&smem[(wm + i*16 + lr)*32 + lkg*8]);
    #pragma unroll
    for (int j=0;j<4;++j) b[j] = ld8(&smem[4096 + (wn + j*16 + lr)*32 + lkg*8]);
    #pragma unroll
    for (int i=0;i<4;++i)
      #pragma unroll
      for (int j=0;j<4;++j)
        acc[i][j] = __builtin_amdgcn_mfma_f32_16x16x32_bf16(a[i], b[j], acc[i][j], 0, 0, 0);
  }
  // ---- epilogue: LDS restage -> dense 16B coalesced stores ----
  float sw = mw[widx];
  int bb0 = m0 >> 11;
  int h0 = (n0g >> 6) & 15;
  #pragma unroll
  for (int g = 0; g < 4; ++g) {
    __syncthreads();
    if (widx != 2) {
      // row-major staging: phase g = tile rows 32g..32g+31
      if ((w>>1) == (g>>1)) {
        #pragma unroll
        for (int ii = 0; ii < 2; ++ii) {
          int i = (g&1)*2 + ii;
          #pragma unroll
          for (int j = 0; j < 4; ++j) {
            int col = wn + j*16 + lr;
            #pragma unroll
            for (int r = 0; r < 4; ++r) {
              int rloc = ii*16 + lkg*4 + r;
              int row = m0 + g*32 + rloc;
              float v = acc[i][j][r] * rowscale[row] * sw;
              if (widx == 3) v = v / (1.0f + __expf(-v));
              smem[rloc*136 + col] = f2bf(v);
            }
          }
        }
      }
    } else {
      // col-major staging: phase g = tile cols 32g..32g+31, stage[colrel][row]
      if ((w&1) == (g>>1)) {
        #pragma unroll
        for (int jj = 0; jj < 2; ++jj) {
          int j = (g&1)*2 + jj;
          #pragma unroll
          for (int i = 0; i < 4; ++i) {
            #pragma unroll
            for (int r = 0; r < 4; ++r) {
              int rowrel = wm + i*16 + lkg*4 + r;
              float v = acc[i][j][r] * rowscale[m0 + rowrel] * sw;
              smem[(jj*16 + lr)*136 + rowrel] = f2bf(v);
            }
          }
        }
      }
    }
    __syncthreads();
    #pragma unroll
    for (int u = 0; u < 2; ++u) {
      int c = u*256 + tid;
      int rr = c >> 4, k8 = c & 15;
      uint4 val = *(const uint4*)&smem[rr*136 + k8*8];
      if (widx <= 1) {
        int row = m0 + g*32 + rr;
        int n = row & 2047;
        int h = h0 + (k8 >> 3);
        int e8 = (k8 & 7)*8;
        u16* dst = widx ? kh : qh;
        *(uint4*)&dst[(((size_t)((row>>11)*H_ + h))*N_ + n)*64 + e8] = val;
      } else if (widx == 2) {
        int ecol = n0g + g*32 + rr;
        int h = (ecol >> 6) & 15, e = ecol & 63;
        int n8 = (m0 & 2047) + k8*8;
        *(uint4*)&vhT[(((size_t)(bb0*H_ + h))*64 + e)*N_ + n8] = val;
      } else {
        int row = m0 + g*32 + rr;
        int d = (n0g & 1023) + k8*8;
        *(uint4*)&gbufH[(size_t)row*D_ + d] = val;
      }
    }
  }
}

// ---------- retention phase A: per-chunk state contribution ----------
// M_c[dv][dk] = sum_j gamma^(64-j) * v[c*64+j][dv] * k[c*64+j][dk]   (f32)
__global__ __launch_bounds__(256) void k_state(const u16* __restrict__ kh, const u16* __restrict__ vhT,
                       float* __restrict__ Mbuf, GammaArg G) {
  __shared__ u16 kT[64][72];   // [dk][j]
  int c = blockIdx.x, bh = blockIdx.y;
  float lg = G.lg2[bh & 15];
  int tid = threadIdx.x, w = tid>>6, l = tid&63;
  int lr = l&15, lkg = l>>4;
  const size_t base = (size_t)bh * (N_*64);
  // stage K^T (transpose via LDS)
  {
    int j = tid>>2, cs = (tid&3)*16;
    const u16* kp = kh + base + (size_t)(c*64 + j)*64 + cs;
    uint4 u0 = *(const uint4*)kp;
    uint4 u1 = *(const uint4*)(kp + 8);
    const u16* s0 = (const u16*)&u0;
    const u16* s1 = (const u16*)&u1;
    #pragma unroll
    for (int m2=0;m2<8;++m2) kT[cs+m2][j] = s0[m2];
    #pragma unroll
    for (int m2=0;m2<8;++m2) kT[cs+8+m2][j] = s1[m2];
  }
  __syncthreads();
  // weighted V^T fragments, hi/lo bf16 split
  bf16x8 ah[2], al[2];
  #pragma unroll
  for (int kk=0;kk<2;++kk) {
    bf16x8 raw = ld8(vhT + base + (size_t)(w*16 + lr)*N_ + c*64 + kk*32 + lkg*8);
    #pragma unroll
    for (int m2=0;m2<8;++m2) {
      int j = kk*32 + lkg*8 + m2;
      float wj = exp2f((float)(64 - j) * lg);
      float p = bf2f((u16)raw[m2]) * wj;
      u16 hh = f2bf(p);
      ah[kk][m2] = (short)hh;
      al[kk][m2] = (short)f2bf(p - bf2f(hh));
    }
  }
  f32x4 macc[4];
  for (int t=0;t<4;++t) macc[t] = (f32x4){0.f,0.f,0.f,0.f};
  #pragma unroll
  for (int t=0;t<4;++t)
    #pragma unroll
    for (int kk=0;kk<2;++kk) {
      bf16x8 b = ld8(&kT[t*16 + lr][kk*32 + lkg*8]);
      macc[t] = __builtin_amdgcn_mfma_f32_16x16x32_bf16(ah[kk], b, macc[t], 0,0,0);
      macc[t] = __builtin_amdgcn_mfma_f32_16x16x32_bf16(al[kk], b, macc[t], 0,0,0);
    }
  float* mp = Mbuf + (size_t)(bh*32 + c)*4096;
  for (int t=0;t<4;++t) {
    #pragma unroll
    for (int r=0;r<4;++r)
      mp[(w*16 + lkg*4 + r)*64 + t*16 + lr] = macc[t][r];
  }
}

// ---------- retention scan: S_c = g64*S_{c-1} + M_{c-1}, store bf16 hi/lo ----------
__global__ void k_scan(const float* __restrict__ Mbuf, u16* __restrict__ Shi, u16* __restrict__ Slo, GammaArg G) {
  int bx = blockIdx.x, bh = blockIdx.y;
  float g64 = exp2f(64.0f * G.lg2[bh & 15]);
  int e = bx*256 + threadIdx.x;
  size_t eb = (size_t)bh*32*4096 + e;
  float S = 0.0f;
  Shi[eb] = 0; Slo[eb] = 0;
  #pragma unroll
  for (int c = 1; c < 32; ++c) {
    S = g64*S + Mbuf[eb + (size_t)(c-1)*4096];
    u16 hh = f2bf(S);
    Shi[eb + (size_t)c*4096] = hh;
    Slo[eb + (size_t)c*4096] = f2bf(S - bf2f(hh));
  }
}

// ---------- retention phase B: y = gamma^i * q . S  +  local (masked decay) ----------
__global__ __launch_bounds__(256) void k_retB(const u16* __restrict__ qh, const u16* __restrict__ kh,
                       const u16* __restrict__ vhT, const u16* __restrict__ Shi, const u16* __restrict__ Slo,
                       float* __restrict__ y, GammaArg G) {
  __shared__ u16 pl[4][16][76];
  int c = blockIdx.x, bh = blockIdx.y;
  int b = bh >> 4, h = bh & 15;
  float lg = G.lg2[h];
  int tid = threadIdx.x, w = tid>>6, l = tid&63;
  int lr = l&15, lkg = l>>4;
  const size_t base = (size_t)bh * (N_*64);
  int nl_base = w*16 + lkg*4;
  // Q fragments
  bf16x8 qa[2];
  {
    const u16* qp = qh + base + (size_t)(c*64 + w*16 + lr)*64 + lkg*8;
    qa[0] = ld8(qp);
    qa[1] = ld8(qp + 32);
  }
  // cross: yc = q . (S_hi + S_lo)
  f32x4 yc[4];
  for (int t=0;t<4;++t) yc[t] = (f32x4){0.f,0.f,0.f,0.f};
  {
    const u16* sp = Shi + (size_t)(bh*32 + c)*4096;
    const u16* sq = Slo + (size_t)(bh*32 + c)*4096;
    #pragma unroll
    for (int kk=0;kk<2;++kk)
      #pragma unroll
      for (int t=0;t<4;++t) {
        int off = (t*16 + lr)*64 + kk*32 + lkg*8;
        yc[t] = __builtin_amdgcn_mfma_f32_16x16x32_bf16(qa[kk], ld8(sp + off), yc[t], 0,0,0);
        yc[t] = __builtin_amdgcn_mfma_f32_16x16x32_bf16(qa[kk], ld8(sq + off), yc[t], 0,0,0);
      }
  }
  // local: S_loc = Q K^T (diag tile), masked decay, P in LDS, then P V
  f32x4 sacc[4];
  for (int jt=0;jt<4;++jt) sacc[jt] = (f32x4){0.f,0.f,0.f,0.f};
  #pragma unroll
  for (int jt=0;jt<4;++jt) {
    const u16* kp = kh + base + (size_t)(c*64 + jt*16 + lr)*64 + lkg*8;
    sacc[jt] = __builtin_amdgcn_mfma_f32_16x16x32_bf16(qa[0], ld8(kp),    sacc[jt], 0,0,0);
    sacc[jt] = __builtin_amdgcn_mfma_f32_16x16x32_bf16(qa[1], ld8(kp+32), sacc[jt], 0,0,0);
  }
  #pragma unroll
  for (int jt=0;jt<4;++jt)
    #pragma unroll
    for (int r=0;r<4;++r) {
      int d = (nl_base + r) - (jt*16 + lr);
      float p = (d >= 0) ? sacc[jt][r]*0.125f*exp2f((float)d*lg) : 0.0f;
      pl[w][lkg*4+r][jt*16+lr] = f2bf(p);
    }
  f32x4 yacc[4];
  for (int t=0;t<4;++t) yacc[t] = (f32x4){0.f,0.f,0.f,0.f};
  #pragma unroll
  for (int kk2=0;kk2<2;++kk2) {
    bf16x8 pa = *(bf16x8*)&pl[w][lr][kk2*32 + lkg*8];
    #pragma unroll
    for (int t=0;t<4;++t) {
      bf16x8 vb = ld8(vhT + base + (size_t)(t*16 + lr)*N_ + c*64 + kk2*32 + lkg*8);
      yacc[t] = __builtin_amdgcn_mfma_f32_16x16x32_bf16(pa, vb, yacc[t], 0,0,0);
    }
  }
  float cw[4];
  #pragma unroll
  for (int r=0;r<4;++r) cw[r] = 0.125f * exp2f((float)(nl_base + r) * lg);
  for (int t=0;t<4;++t) {
    #pragma unroll
    for (int r=0;r<4;++r) {
      int n = c*64 + nl_base + r;
      int col = h*64 + t*16 + lr;
      y[((size_t)(b*N_ + n))*D_ + col] = yacc[t][r] + cw[r]*yc[t][r];
    }
  }
}

// ---------- MFMA GEMM (128x64 tile) for final wo projection (f32 out) ----------
__global__ __launch_bounds__(256, 4) void k_gemm(const u16* __restrict__ A, const u16* __restrict__ Bt,
                       const float* __restrict__ rowscale, const float* __restrict__ mw, int widx,
                       float* __restrict__ outF) {
  __shared__ u16 As[128*32];
  __shared__ u16 Bs[64*32];
  int tid = threadIdx.x;
  // XCD-chunked bijective swizzle: 512 blocks (32x16), 64 per XCD.
  int flat = blockIdx.y * gridDim.x + blockIdx.x;
  int swz = (flat & 7) * 64 + (flat >> 3);
  int m0 = (swz & 31)*128, n0 = (swz >> 5)*64;
  int w = tid>>6, l = tid&63;
  int wm = (w>>1)*64, wn = (w&1)*32;
  int lr = l&15, lkg = l>>4;
  f32x4 acc[4][2];
  for (int i=0;i<4;++i) for (int j=0;j<2;++j) acc[i][j] = (f32x4){0.f,0.f,0.f,0.f};
  int c0 = tid, c1 = tid + 256;
  const u16* ga0 = A  + (size_t)(m0 + (c0>>2))*D_ + (c0&3)*8;
  const u16* ga1 = A  + (size_t)(m0 + (c1>>2))*D_ + (c1&3)*8;
  const u16* gb0 = Bt + (size_t)(n0 + (c0>>2))*D_ + (c0&3)*8;
  for (int k0 = 0; k0 < D_; k0 += 32) {
    __syncthreads();
    GLDS(ga0 + k0, &As[w*512]);
    GLDS(ga1 + k0, &As[2048 + w*512]);
    GLDS(gb0 + k0, &Bs[w*512]);
    __syncthreads();
    bf16x8 a[4], b[2];
    for (int i=0;i<4;++i) a[i] = ld8(&As[(wm + i*16 + lr)*32 + lkg*8]);
    for (int j=0;j<2;++j) b[j] = ld8(&Bs[(wn + j*16 + lr)*32 + lkg*8]);
    for (int i=0;i<4;++i)
      for (int j=0;j<2;++j)
        acc[i][j] = __builtin_amdgcn_mfma_f32_16x16x32_bf16(a[i], b[j], acc[i][j], 0, 0, 0);
  }
  float sw = mw[widx];
  for (int i=0;i<4;++i) {
    int rowb = m0 + wm + i*16 + lkg*4;
    for (int j=0;j<2;++j) {
      int col = n0 + wn + j*16 + lr;
      #pragma unroll
      for (int r=0;r<4;++r)
        outF[(size_t)(rowb+r)*D_ + col] = acc[i][j][r] * rowscale[rowb+r] * sw;
    }
  }
}

// ---------- row LayerNorm(y)*g -> z, plus per-row z sums (g is bf16) ----------
__global__ void k_ln_mul(const float* __restrict__ y, const u16* __restrict__ gH,
                         const float* __restrict__ lnw, const float* __restrict__ lnb,
                         float* __restrict__ z, double* __restrict__ zrow) {
  int m = blockIdx.x, t = threadIdx.x;
  float4 v = *(const float4*)(y + (size_t)m*D_ + t*4);
  double s  = (double)v.x + (double)v.y + (double)v.z + (double)v.w;
  double s2 = (double)v.x*v.x + (double)v.y*v.y + (double)v.z*v.z + (double)v.w*v.w;
  __shared__ double lds[8];
  int w = t>>6, l = t&63;
  for (int o = 32; o > 0; o >>= 1) { s += __shfl_down(s,o); s2 += __shfl_down(s2,o); }
  if (l==0) { lds[w*2]=s; lds[w*2+1]=s2; }
  __syncthreads();
  double ts = lds[0]+lds[2]+lds[4]+lds[6], ts2 = lds[1]+lds[3]+lds[5]+lds[7];
  float mu = (float)(ts/(double)D_);
  float var = (float)(ts2/(double)D_) - mu*mu;
  float rstd = rsqrtf(var + 1e-5f);
  ushort4 gv4 = *(const ushort4*)(gH + (size_t)m*D_ + t*4);
  float g0 = bf2f(gv4.x), g1 = bf2f(gv4.y), g2 = bf2f(gv4.z), g3 = bf2f(gv4.w);
  float4 lw = *(const float4*)(lnw + t*4);
  float4 lb = *(const float4*)(lnb + t*4);
  float z0 = ((v.x-mu)*rstd*lw.x + lb.x)*g0;
  float z1 = ((v.y-mu)*rstd*lw.y + lb.y)*g1;
  float z2 = ((v.z-mu)*rstd*lw.z + lb.z)*g2;
  float z3 = ((v.w-mu)*rstd*lw.w + lb.w)*g3;
  float4 zo; zo.x=z0; zo.y=z1; zo.z=z2; zo.w=z3;
  *(float4*)(z + (size_t)m*D_ + t*4) = zo;
  double zs  = (double)z0 + (double)z1 + (double)z2 + (double)z3;
  double zs2 = (double)z0*z0 + (double)z1*z1 + (double)z2*z2 + (double)z3*z3;
  for (int o = 32; o > 0; o >>= 1) { zs += __shfl_down(zs,o); zs2 += __shfl_down(zs2,o); }
  __syncthreads();
  if (l==0) { lds[w*2]=zs; lds[w*2+1]=zs2; }
  __syncthreads();
  if (t==0) {
    zrow[m*2]   = lds[0]+lds[2]+lds[4]+lds[6];
    zrow[m*2+1] = lds[1]+lds[3]+lds[5]+lds[7];
  }
}

__global__ void k_zstats_final(const double* __restrict__ zrow, float* __restrict__ stats) {
  int b = blockIdx.x, t = threadIdx.x; // 256
  double s=0.0, s2=0.0;
  for (int k=0;k<8;++k) {
    int m = b*2048 + k*256 + t;
    s += zrow[m*2]; s2 += zrow[m*2+1];
  }
  for (int o = 32; o > 0; o >>= 1) { s += __shfl_down(s,o); s2 += __shfl_down(s2,o); }
  __shared__ double lds[8];
  int w = t>>6, l = t&63;
  if (l==0) { lds[w*2]=s; lds[w*2+1]=s2; }
  __syncthreads();
  if (t==0) {
    double ts = lds[0]+lds[2]+lds[4]+lds[6], ts2 = lds[1]+lds[3]+lds[5]+lds[7];
    double inv = 1.0/(double)(N_*D_);
    double mu = ts*inv, var = ts2*inv - mu*mu;
    stats[b*2]   = (float)mu;
    stats[b*2+1] = rsqrtf((float)var + 1e-5f);
  }
}

extern "C" void kernel_launch(void* const* d_in, const int* in_sizes, int n_in,
                              void* d_out, int out_size, void* d_ws, size_t ws_size,
                              hipStream_t stream) {
  const float* x = (const float*)d_in[0];
  Ptr5 W;
  for (int i = 0; i < 5; ++i) W.p[i] = (const float*)d_in[1+i];
  const float* lnw = (const float*)d_in[6];
  const float* lnb = (const float*)d_in[7];

  char* ws = (char*)d_ws;
  float*  xstats = (float*)(ws + 0);
  float*  zstats = (float*)(ws + 64);
  float*  mw     = (float*)(ws + 128);
  float*  invmw  = (float*)(ws + 192);
  double* part1  = (double*)(ws + 256);      // 128*2 doubles
  double* wpart  = (double*)(ws + 2304);     // 80 doubles
  float*  inv1   = (float*)(ws + 3072);      // 4096
  float*  inv2   = (float*)(ws + 19456);     // 4096
  double* zrow   = (double*)(ws + 35840);    // 4096*2
  u16*    wt     = (u16*)(ws + 101376);      // 5*1M bf16 (10.49 MB)
  u16*    qx     = (u16*)(ws + 10587136);    // 4096x1024 bf16 (8.39 MB)
  u16*    qh     = (u16*)(ws + 18975744);
  u16*    kh     = (u16*)(ws + 27364352);
  u16*    vhT    = (u16*)(ws + 35752960);    // [B,H,64,N]
  u16*    gbufH  = (u16*)(ws + 44141568);    // bf16 [M,D] 8.39 MB
  float*  ybuf   = (float*)(ws + 60918784);  // f32 16.78 MB
  float*  zbuf   = (float*)(ws + 77696000);  // f32 16.78 MB
  // aliases (lifetimes verified against dispatch order):
  float*  Mbuf   = (float*)(ws + 77696000);  // = zbuf region; consumed by scan before ln_mul writes z
  u16*    Shi    = (u16*)(ws + 10587136);    // = qx region; qx dead after fused GEMM
  u16*    Slo    = (u16*)(ws + 101376);      // = wt matrices 0-3; dead after fused GEMM; wo weights untouched
  u16*    qz     = qx;

  GammaArg G;
  {
    double l0 = log(1.0/32.0), l1 = log(1.0/512.0);
    for (int h = 0; h < 16; ++h) {
      float t = (float)(l0 + (l1-l0)*((double)h/15.0));
      float gm = 1.0f - expf(t);
      G.lg2[h] = (float)log2((double)gm);
    }
  }

  dim3 b256(256);
  hipLaunchKernelGGL(k_batch_stats_partial, dim3(64, B_), b256, 0, stream, x, part1);
  hipLaunchKernelGGL(k_batch_stats_final, dim3(B_), dim3(64), 0, stream, part1, xstats);
  hipLaunchKernelGGL(k_wmean_partial, dim3(16, 5), b256, 0, stream, W, wpart);
  hipLaunchKernelGGL(k_wmean_final, dim3(5), dim3(64), 0, stream, wpart, mw, invmw);
  hipLaunchKernelGGL(k_ternarize, dim3(1024, 5), b256, 0, stream, W, invmw, wt);
  hipLaunchKernelGGL(k_quant_rows, dim3(M_), b256, 0, stream, x, xstats, qx, inv1);

  hipLaunchKernelGGL(k_gemm_qkvg, dim3(32, 32), b256, 0, stream, qx, wt, inv1, mw, qh, kh, vhT, gbufH);

  hipLaunchKernelGGL(k_state, dim3(32, 32), b256, 0, stream, kh, vhT, Mbuf, G);
  hipLaunchKernelGGL(k_scan, dim3(16, 32), b256, 0, stream, Mbuf, Shi, Slo, G);
  hipLaunchKernelGGL(k_retB, dim3(32, 32), b256, 0, stream, qh, kh, vhT, Shi, Slo, ybuf, G);

  hipLaunchKernelGGL(k_ln_mul, dim3(M_), b256, 0, stream, ybuf, gbufH, lnw, lnb, zbuf, zrow);
  hipLaunchKernelGGL(k_zstats_final, dim3(B_), b256, 0, stream, zrow, zstats);
  hipLaunchKernelGGL(k_quant_rows, dim3(M_), b256, 0, stream, zbuf, zstats, qz, inv2);
  hipLaunchKernelGGL(k_gemm, dim3(32,16), b256, 0, stream, qz, wt + (size_t)4*1048576, inv2, mw, 4, (float*)d_out);
}

// Round 8
// 236.651 us; speedup vs baseline: 2.0984x; 1.0075x over previous
//
#include <hip/hip_runtime.h>
#include <math.h>

#define B_ 2
#define N_ 2048
#define D_ 1024
#define H_ 16
#define M_ (B_*N_)

typedef unsigned short u16;
typedef unsigned int u32;
typedef short bf16x8 __attribute__((ext_vector_type(8)));
typedef float f32x4 __attribute__((ext_vector_type(4)));

struct Ptr5 { const float* p[5]; };
struct GammaArg { float lg2[16]; };

static __device__ inline u16 f2bf(float f) {
  union { float f; unsigned u; } x; x.f = f;
  unsigned u = x.u;
  unsigned r = (u + 0x7fffu + ((u >> 16) & 1u)) >> 16;
  return (u16)r;
}
static __device__ inline float bf2f(u16 h) {
  union { unsigned u; float f; } x; x.u = ((unsigned)h) << 16; return x.f;
}
static __device__ inline bf16x8 ld8(const u16* p) {
  uint4 u = *(const uint4*)(p);
  return *reinterpret_cast<bf16x8*>(&u);
}
#define GLDS(g, l) __builtin_amdgcn_global_load_lds((const __attribute__((address_space(1))) u32*)(g), (__attribute__((address_space(3))) u32*)(l), 16, 0, 0)

// ---------- fused partial stats: x batch stats (blocks 0..127) + weight abs-mean (blocks 128..207) ----------
__global__ void k_stats_all(const float* __restrict__ x, Ptr5 W,
                            double* __restrict__ part1, double* __restrict__ wpart) {
  int bx = blockIdx.x, t = threadIdx.x;
  int w = t>>6, l = t&63;
  __shared__ double lds[8];
  if (bx < 128) {
    int b = bx >> 6, c = bx & 63;
    const float* p = x + (size_t)b*(N_*D_) + (size_t)c*32768;
    double s = 0.0, s2 = 0.0;
    for (int it = 0; it < 32; ++it) {
      float4 v = *(const float4*)(p + it*1024 + t*4);
      s  += (double)v.x + (double)v.y + (double)v.z + (double)v.w;
      s2 += (double)v.x*v.x + (double)v.y*v.y + (double)v.z*v.z + (double)v.w*v.w;
    }
    for (int o = 32; o > 0; o >>= 1) { s += __shfl_down(s,o); s2 += __shfl_down(s2,o); }
    if (l==0) { lds[w*2]=s; lds[w*2+1]=s2; }
    __syncthreads();
    if (t==0) {
      part1[(b*64+c)*2]   = lds[0]+lds[2]+lds[4]+lds[6];
      part1[(b*64+c)*2+1] = lds[1]+lds[3]+lds[5]+lds[7];
    }
  } else {
    int i = bx - 128;
    int wi = i >> 4, c = i & 15;
    const float* p = W.p[wi] + (size_t)c*65536;
    double s = 0.0;
    for (int it = 0; it < 64; ++it) {
      float4 v = *(const float4*)(p + it*1024 + t*4);
      s += fabs((double)v.x)+fabs((double)v.y)+fabs((double)v.z)+fabs((double)v.w);
    }
    for (int o = 32; o > 0; o >>= 1) s += __shfl_down(s,o);
    if (l==0) lds[w]=s;
    __syncthreads();
    if (t==0) wpart[wi*16+c] = lds[0]+lds[1]+lds[2]+lds[3];
  }
}

// ---------- fused finals: xstats (waves 0-1) + mw/invmw (waves 2-3) ----------
__global__ void k_finals(const double* __restrict__ part1, const double* __restrict__ wpart,
                         float* __restrict__ xstats, float* __restrict__ mw, float* __restrict__ invmw) {
  int t = threadIdx.x;
  int w = t>>6, l = t&63;
  if (w < 2) {
    double s = part1[(w*64+l)*2], s2 = part1[(w*64+l)*2+1];
    for (int o = 32; o > 0; o >>= 1) { s += __shfl_down(s,o); s2 += __shfl_down(s2,o); }
    if (l==0) {
      double inv = 1.0/(double)(N_*D_);
      double mu = s*inv, var = s2*inv - mu*mu;
      xstats[w*2]   = (float)mu;
      xstats[w*2+1] = rsqrtf((float)var + 1e-5f);
    }
  } else {
    int idx = (w-2)*4 + (l>>4);
    int j = l&15;
    if (idx < 5) {
      double s = wpart[idx*16+j];
      for (int o = 8; o > 0; o >>= 1) s += __shfl_down(s,o);
      if (j==0) {
        double mean = s / (double)(D_*D_);
        float mwc = fmaxf((float)mean, 1e-5f);
        mw[idx] = mwc;
        invmw[idx] = 1.0f/mwc;
      }
    }
  }
}

// ---------- fused ternarize (blocks 0..5119) + x row-quant (blocks 5120..9215) ----------
__global__ void k_ternquant(Ptr5 W, const float* __restrict__ invmw, u16* __restrict__ wt,
                            const float* __restrict__ x, const float* __restrict__ xstats,
                            u16* __restrict__ qx, float* __restrict__ inv1) {
  int bx = blockIdx.x, t = threadIdx.x;
  if (bx < 5120) {
    int wi = bx >> 10;
    float inv = invmw[wi];
    size_t off = (size_t)(bx & 1023)*1024 + t*4;
    float4 v = *(const float4*)(W.p[wi] + off);
    ushort4 o4;
    o4.x = f2bf(fminf(fmaxf(rintf(v.x*inv),-1.f),1.f));
    o4.y = f2bf(fminf(fmaxf(rintf(v.y*inv),-1.f),1.f));
    o4.z = f2bf(fminf(fmaxf(rintf(v.z*inv),-1.f),1.f));
    o4.w = f2bf(fminf(fmaxf(rintf(v.w*inv),-1.f),1.f));
    *(ushort4*)(wt + (size_t)wi*(D_*D_) + off) = o4;
  } else {
    int m = bx - 5120;
    int b = m >> 11;
    float mu = xstats[b*2], rstd = xstats[b*2+1];
    float4 v = *(const float4*)(x + (size_t)m*D_ + t*4);
    float xn0 = (v.x-mu)*rstd, xn1 = (v.y-mu)*rstd, xn2 = (v.z-mu)*rstd, xn3 = (v.w-mu)*rstd;
    float am = fmaxf(fmaxf(fabsf(xn0),fabsf(xn1)),fmaxf(fabsf(xn2),fabsf(xn3)));
    for (int o = 32; o > 0; o >>= 1) am = fmaxf(am, __shfl_xor(am,o));
    __shared__ float wm[4];
    int w = t>>6, l = t&63;
    if (l==0) wm[w]=am;
    __syncthreads();
    am = fmaxf(fmaxf(wm[0],wm[1]),fmaxf(wm[2],wm[3]));
    float clipped = fmaxf(am, 1e-5f);
    float sc = 127.0f/clipped;
    ushort4 o4;
    o4.x = f2bf(fminf(fmaxf(rintf(xn0*sc),-128.f),127.f));
    o4.y = f2bf(fminf(fmaxf(rintf(xn1*sc),-128.f),127.f));
    o4.z = f2bf(fminf(fmaxf(rintf(xn2*sc),-128.f),127.f));
    o4.w = f2bf(fminf(fmaxf(rintf(xn3*sc),-128.f),127.f));
    *(ushort4*)(qx + (size_t)m*D_ + t*4) = o4;
    if (t==0) inv1[m] = clipped/127.0f;
  }
}

// ---------- per-row activation quant (z path) ----------
__global__ void k_quant_rows(const float* __restrict__ in, const float* __restrict__ stats,
                             u16* __restrict__ q, float* __restrict__ rowscale) {
  int m = blockIdx.x, t = threadIdx.x;
  int b = m >> 11;
  float mu = stats[b*2], rstd = stats[b*2+1];
  float4 v = *(const float4*)(in + (size_t)m*D_ + t*4);
  float xn0 = (v.x-mu)*rstd, xn1 = (v.y-mu)*rstd, xn2 = (v.z-mu)*rstd, xn3 = (v.w-mu)*rstd;
  float am = fmaxf(fmaxf(fabsf(xn0),fabsf(xn1)),fmaxf(fabsf(xn2),fabsf(xn3)));
  for (int o = 32; o > 0; o >>= 1) am = fmaxf(am, __shfl_xor(am,o));
  __shared__ float wm[4];
  int w = t>>6, l = t&63;
  if (l==0) wm[w]=am;
  __syncthreads();
  am = fmaxf(fmaxf(wm[0],wm[1]),fmaxf(wm[2],wm[3]));
  float clipped = fmaxf(am, 1e-5f);
  float sc = 127.0f/clipped;
  ushort4 o4;
  o4.x = f2bf(fminf(fmaxf(rintf(xn0*sc),-128.f),127.f));
  o4.y = f2bf(fminf(fmaxf(rintf(xn1*sc),-128.f),127.f));
  o4.z = f2bf(fminf(fmaxf(rintf(xn2*sc),-128.f),127.f));
  o4.w = f2bf(fminf(fmaxf(rintf(xn3*sc),-128.f),127.f));
  *(ushort4*)(q + (size_t)m*D_ + t*4) = o4;
  if (t==0) rowscale[m] = clipped/127.0f;
}

// ---------- fused q/k/v/g GEMM: 128x128 tile, BK=64, XOR-swizzled LDS, dense epilogue ----------
__global__ __launch_bounds__(256, 4) void k_gemm_qkvg(const u16* __restrict__ A, const u16* __restrict__ Wt,
                       const float* __restrict__ rowscale, const float* __restrict__ mw,
                       u16* __restrict__ qh, u16* __restrict__ kh, u16* __restrict__ vhT,
                       u16* __restrict__ gbufH) {
  __shared__ u16 smem[16384];   // As [128][64] @0, Bs [128][64] @8192 (XOR-swizzled slots)
  int tid = threadIdx.x;
  int flat = blockIdx.y * gridDim.x + blockIdx.x;
  int swz = (flat & 7) * 128 + (flat >> 3);
  int mxi = swz & 31, nyi = swz >> 5;
  int m0 = mxi*128, n0g = nyi*128;
  int widx = nyi >> 3;
  int w = tid>>6, l = tid&63;
  int wm = (w>>1)*64, wn = (w&1)*64;
  int lr = l&15, lkg = l>>4;
  f32x4 acc[4][4];
  for (int i=0;i<4;++i) for (int j=0;j<4;++j) acc[i][j] = (f32x4){0.f,0.f,0.f,0.f};
  // staging: 1024 chunks/tile; chunk c -> row=c>>3, lds slot=c&7, global slot = (c&7)^(row&7)
  const u16* gaS[4]; const u16* gbS[4];
  #pragma unroll
  for (int i=0;i<4;++i) {
    int c = i*256 + tid;
    int row = c>>3, sslot = (c&7) ^ (row&7);
    gaS[i] = A  + (size_t)(m0 + row)*D_ + sslot*8;
    gbS[i] = Wt + (size_t)(n0g + row)*D_ + sslot*8;
  }
  for (int k0 = 0; k0 < D_; k0 += 64) {
    __syncthreads();
    #pragma unroll
    for (int i=0;i<4;++i) {
      GLDS(gaS[i] + k0, &smem[i*2048 + w*512]);
      GLDS(gbS[i] + k0, &smem[8192 + i*2048 + w*512]);
    }
    __syncthreads();
    #pragma unroll
    for (int kk=0;kk<2;++kk) {
      int s = kk*4 + lkg;
      bf16x8 a[4], b[4];
      #pragma unroll
      for (int i=0;i<4;++i) {
        int r = wm + i*16 + lr;
        a[i] = ld8(&smem[r*64 + (s ^ (r&7))*8]);
      }
      #pragma unroll
      for (int j=0;j<4;++j) {
        int r = wn + j*16 + lr;
        b[j] = ld8(&smem[8192 + r*64 + (s ^ (r&7))*8]);
      }
      #pragma unroll
      for (int i=0;i<4;++i)
        #pragma unroll
        for (int j=0;j<4;++j)
          acc[i][j] = __builtin_amdgcn_mfma_f32_16x16x32_bf16(a[i], b[j], acc[i][j], 0, 0, 0);
    }
  }
  // ---- epilogue: LDS restage -> dense 16B coalesced stores ----
  float sw = mw[widx];
  int bb0 = m0 >> 11;
  int h0 = (n0g >> 6) & 15;
  #pragma unroll
  for (int g = 0; g < 4; ++g) {
    __syncthreads();
    if (widx != 2) {
      if ((w>>1) == (g>>1)) {
        #pragma unroll
        for (int ii = 0; ii < 2; ++ii) {
          int i = (g&1)*2 + ii;
          #pragma unroll
          for (int j = 0; j < 4; ++j) {
            int col = wn + j*16 + lr;
            #pragma unroll
            for (int r = 0; r < 4; ++r) {
              int rloc = ii*16 + lkg*4 + r;
              int row = m0 + g*32 + rloc;
              float v = acc[i][j][r] * rowscale[row] * sw;
              if (widx == 3) v = v / (1.0f + __expf(-v));
              smem[rloc*136 + col] = f2bf(v);
            }
          }
        }
      }
    } else {
      if ((w&1) == (g>>1)) {
        #pragma unroll
        for (int jj = 0; jj < 2; ++jj) {
          int j = (g&1)*2 + jj;
          #pragma unroll
          for (int i = 0; i < 4; ++i) {
            #pragma unroll
            for (int r = 0; r < 4; ++r) {
              int rowrel = wm + i*16 + lkg*4 + r;
              float v = acc[i][j][r] * rowscale[m0 + rowrel] * sw;
              smem[(jj*16 + lr)*136 + rowrel] = f2bf(v);
            }
          }
        }
      }
    }
    __syncthreads();
    #pragma unroll
    for (int u = 0; u < 2; ++u) {
      int c = u*256 + tid;
      int rr = c >> 4, k8 = c & 15;
      uint4 val = *(const uint4*)&smem[rr*136 + k8*8];
      if (widx <= 1) {
        int row = m0 + g*32 + rr;
        int n = row & 2047;
        int h = h0 + (k8 >> 3);
        int e8 = (k8 & 7)*8;
        u16* dst = widx ? kh : qh;
        *(uint4*)&dst[(((size_t)((row>>11)*H_ + h))*N_ + n)*64 + e8] = val;
      } else if (widx == 2) {
        int ecol = n0g + g*32 + rr;
        int h = (ecol >> 6) & 15, e = ecol & 63;
        int n8 = (m0 & 2047) + k8*8;
        *(uint4*)&vhT[(((size_t)(bb0*H_ + h))*64 + e)*N_ + n8] = val;
      } else {
        int row = m0 + g*32 + rr;
        int d = (n0g & 1023) + k8*8;
        *(uint4*)&gbufH[(size_t)row*D_ + d] = val;
      }
    }
  }
}

// ---------- retention phase A: per-chunk state contribution ----------
__global__ __launch_bounds__(256) void k_state(const u16* __restrict__ kh, const u16* __restrict__ vhT,
                       float* __restrict__ Mbuf, GammaArg G) {
  __shared__ u16 kT[64][72];   // [dk][j]
  int c = blockIdx.x, bh = blockIdx.y;
  float lg = G.lg2[bh & 15];
  int tid = threadIdx.x, w = tid>>6, l = tid&63;
  int lr = l&15, lkg = l>>4;
  const size_t base = (size_t)bh * (N_*64);
  {
    int j = tid>>2, cs = (tid&3)*16;
    const u16* kp = kh + base + (size_t)(c*64 + j)*64 + cs;
    uint4 u0 = *(const uint4*)kp;
    uint4 u1 = *(const uint4*)(kp + 8);
    const u16* s0 = (const u16*)&u0;
    const u16* s1 = (const u16*)&u1;
    #pragma unroll
    for (int m2=0;m2<8;++m2) kT[cs+m2][j] = s0[m2];
    #pragma unroll
    for (int m2=0;m2<8;++m2) kT[cs+8+m2][j] = s1[m2];
  }
  __syncthreads();
  bf16x8 ah[2], al[2];
  #pragma unroll
  for (int kk=0;kk<2;++kk) {
    bf16x8 raw = ld8(vhT + base + (size_t)(w*16 + lr)*N_ + c*64 + kk*32 + lkg*8);
    #pragma unroll
    for (int m2=0;m2<8;++m2) {
      int j = kk*32 + lkg*8 + m2;
      float wj = exp2f((float)(64 - j) * lg);
      float p = bf2f((u16)raw[m2]) * wj;
      u16 hh = f2bf(p);
      ah[kk][m2] = (short)hh;
      al[kk][m2] = (short)f2bf(p - bf2f(hh));
    }
  }
  f32x4 macc[4];
  for (int t=0;t<4;++t) macc[t] = (f32x4){0.f,0.f,0.f,0.f};
  #pragma unroll
  for (int t=0;t<4;++t)
    #pragma unroll
    for (int kk=0;kk<2;++kk) {
      bf16x8 b = ld8(&kT[t*16 + lr][kk*32 + lkg*8]);
      macc[t] = __builtin_amdgcn_mfma_f32_16x16x32_bf16(ah[kk], b, macc[t], 0,0,0);
      macc[t] = __builtin_amdgcn_mfma_f32_16x16x32_bf16(al[kk], b, macc[t], 0,0,0);
    }
  float* mp = Mbuf + (size_t)(bh*32 + c)*4096;
  for (int t=0;t<4;++t) {
    #pragma unroll
    for (int r=0;r<4;++r)
      mp[(w*16 + lkg*4 + r)*64 + t*16 + lr] = macc[t][r];
  }
}

// ---------- retention scan ----------
__global__ void k_scan(const float* __restrict__ Mbuf, u16* __restrict__ Shi, u16* __restrict__ Slo, GammaArg G) {
  int bx = blockIdx.x, bh = blockIdx.y;
  float g64 = exp2f(64.0f * G.lg2[bh & 15]);
  int e = bx*256 + threadIdx.x;
  size_t eb = (size_t)bh*32*4096 + e;
  float S = 0.0f;
  Shi[eb] = 0; Slo[eb] = 0;
  #pragma unroll
  for (int c = 1; c < 32; ++c) {
    S = g64*S + Mbuf[eb + (size_t)(c-1)*4096];
    u16 hh = f2bf(S);
    Shi[eb + (size_t)c*4096] = hh;
    Slo[eb + (size_t)c*4096] = f2bf(S - bf2f(hh));
  }
}

// ---------- retention phase B ----------
__global__ __launch_bounds__(256) void k_retB(const u16* __restrict__ qh, const u16* __restrict__ kh,
                       const u16* __restrict__ vhT, const u16* __restrict__ Shi, const u16* __restrict__ Slo,
                       float* __restrict__ y, GammaArg G) {
  __shared__ u16 pl[4][16][76];
  int c = blockIdx.x, bh = blockIdx.y;
  int b = bh >> 4, h = bh & 15;
  float lg = G.lg2[h];
  int tid = threadIdx.x, w = tid>>6, l = tid&63;
  int lr = l&15, lkg = l>>4;
  const size_t base = (size_t)bh * (N_*64);
  int nl_base = w*16 + lkg*4;
  bf16x8 qa[2];
  {
    const u16* qp = qh + base + (size_t)(c*64 + w*16 + lr)*64 + lkg*8;
    qa[0] = ld8(qp);
    qa[1] = ld8(qp + 32);
  }
  f32x4 yc[4];
  for (int t=0;t<4;++t) yc[t] = (f32x4){0.f,0.f,0.f,0.f};
  {
    const u16* sp = Shi + (size_t)(bh*32 + c)*4096;
    const u16* sq = Slo + (size_t)(bh*32 + c)*4096;
    #pragma unroll
    for (int kk=0;kk<2;++kk)
      #pragma unroll
      for (int t=0;t<4;++t) {
        int off = (t*16 + lr)*64 + kk*32 + lkg*8;
        yc[t] = __builtin_amdgcn_mfma_f32_16x16x32_bf16(qa[kk], ld8(sp + off), yc[t], 0,0,0);
        yc[t] = __builtin_amdgcn_mfma_f32_16x16x32_bf16(qa[kk], ld8(sq + off), yc[t], 0,0,0);
      }
  }
  f32x4 sacc[4];
  for (int jt=0;jt<4;++jt) sacc[jt] = (f32x4){0.f,0.f,0.f,0.f};
  #pragma unroll
  for (int jt=0;jt<4;++jt) {
    const u16* kp = kh + base + (size_t)(c*64 + jt*16 + lr)*64 + lkg*8;
    sacc[jt] = __builtin_amdgcn_mfma_f32_16x16x32_bf16(qa[0], ld8(kp),    sacc[jt], 0,0,0);
    sacc[jt] = __builtin_amdgcn_mfma_f32_16x16x32_bf16(qa[1], ld8(kp+32), sacc[jt], 0,0,0);
  }
  #pragma unroll
  for (int jt=0;jt<4;++jt)
    #pragma unroll
    for (int r=0;r<4;++r) {
      int d = (nl_base + r) - (jt*16 + lr);
      float p = (d >= 0) ? sacc[jt][r]*0.125f*exp2f((float)d*lg) : 0.0f;
      pl[w][lkg*4+r][jt*16+lr] = f2bf(p);
    }
  f32x4 yacc[4];
  for (int t=0;t<4;++t) yacc[t] = (f32x4){0.f,0.f,0.f,0.f};
  #pragma unroll
  for (int kk2=0;kk2<2;++kk2) {
    bf16x8 pa = *(bf16x8*)&pl[w][lr][kk2*32 + lkg*8];
    #pragma unroll
    for (int t=0;t<4;++t) {
      bf16x8 vb = ld8(vhT + base + (size_t)(t*16 + lr)*N_ + c*64 + kk2*32 + lkg*8);
      yacc[t] = __builtin_amdgcn_mfma_f32_16x16x32_bf16(pa, vb, yacc[t], 0,0,0);
    }
  }
  float cw[4];
  #pragma unroll
  for (int r=0;r<4;++r) cw[r] = 0.125f * exp2f((float)(nl_base + r) * lg);
  for (int t=0;t<4;++t) {
    #pragma unroll
    for (int r=0;r<4;++r) {
      int n = c*64 + nl_base + r;
      int col = h*64 + t*16 + lr;
      y[((size_t)(b*N_ + n))*D_ + col] = yacc[t][r] + cw[r]*yc[t][r];
    }
  }
}

// ---------- MFMA GEMM (128x64 tile, BK=64, swizzled) for final wo projection ----------
__global__ __launch_bounds__(256, 4) void k_gemm(const u16* __restrict__ A, const u16* __restrict__ Bt,
                       const float* __restrict__ rowscale, const float* __restrict__ mw, int widx,
                       float* __restrict__ outF) {
  __shared__ u16 As[8192];   // [128][64] swizzled
  __shared__ u16 Bs[4096];   // [64][64] swizzled
  int tid = threadIdx.x;
  int flat = blockIdx.y * gridDim.x + blockIdx.x;
  int swz = (flat & 7) * 64 + (flat >> 3);
  int m0 = (swz & 31)*128, n0 = (swz >> 5)*64;
  int w = tid>>6, l = tid&63;
  int wm = (w>>1)*64, wn = (w&1)*32;
  int lr = l&15, lkg = l>>4;
  f32x4 acc[4][2];
  for (int i=0;i<4;++i) for (int j=0;j<2;++j) acc[i][j] = (f32x4){0.f,0.f,0.f,0.f};
  const u16* gaS[4]; const u16* gbS[2];
  #pragma unroll
  for (int i=0;i<4;++i) {
    int c = i*256 + tid;
    int row = c>>3, sslot = (c&7) ^ (row&7);
    gaS[i] = A + (size_t)(m0 + row)*D_ + sslot*8;
    if (i < 2) gbS[i] = Bt + (size_t)(n0 + row)*D_ + sslot*8;
  }
  for (int k0 = 0; k0 < D_; k0 += 64) {
    __syncthreads();
    #pragma unroll
    for (int i=0;i<4;++i) GLDS(gaS[i] + k0, &As[i*2048 + w*512]);
    #pragma unroll
    for (int i=0;i<2;++i) GLDS(gbS[i] + k0, &Bs[i*2048 + w*512]);
    __syncthreads();
    #pragma unroll
    for (int kk=0;kk<2;++kk) {
      int s = kk*4 + lkg;
      bf16x8 a[4], b[2];
      #pragma unroll
      for (int i=0;i<4;++i) {
        int r = wm + i*16 + lr;
        a[i] = ld8(&As[r*64 + (s ^ (r&7))*8]);
      }
      #pragma unroll
      for (int j=0;j<2;++j) {
        int r = wn + j*16 + lr;
        b[j] = ld8(&Bs[r*64 + (s ^ (r&7))*8]);
      }
      #pragma unroll
      for (int i=0;i<4;++i)
        #pragma unroll
        for (int j=0;j<2;++j)
          acc[i][j] = __builtin_amdgcn_mfma_f32_16x16x32_bf16(a[i], b[j], acc[i][j], 0, 0, 0);
    }
  }
  float sw = mw[widx];
  for (int i=0;i<4;++i) {
    int rowb = m0 + wm + i*16 + lkg*4;
    for (int j=0;j<2;++j) {
      int col = n0 + wn + j*16 + lr;
      #pragma unroll
      for (int r=0;r<4;++r)
        outF[(size_t)(rowb+r)*D_ + col] = acc[i][j][r] * rowscale[rowb+r] * sw;
    }
  }
}

// ---------- row LayerNorm(y)*g -> z, plus per-row z sums (g is bf16) ----------
__global__ void k_ln_mul(const float* __restrict__ y, const u16* __restrict__ gH,
                         const float* __restrict__ lnw, const float* __restrict__ lnb,
                         float* __restrict__ z, double* __restrict__ zrow) {
  int m = blockIdx.x, t = threadIdx.x;
  float4 v = *(const float4*)(y + (size_t)m*D_ + t*4);
  double s  = (double)v.x + (double)v.y + (double)v.z + (double)v.w;
  double s2 = (double)v.x*v.x + (double)v.y*v.y + (double)v.z*v.z + (double)v.w*v.w;
  __shared__ double lds[8];
  int w = t>>6, l = t&63;
  for (int o = 32; o > 0; o >>= 1) { s += __shfl_down(s,o); s2 += __shfl_down(s2,o); }
  if (l==0) { lds[w*2]=s; lds[w*2+1]=s2; }
  __syncthreads();
  double ts = lds[0]+lds[2]+lds[4]+lds[6], ts2 = lds[1]+lds[3]+lds[5]+lds[7];
  float mu = (float)(ts/(double)D_);
  float var = (float)(ts2/(double)D_) - mu*mu;
  float rstd = rsqrtf(var + 1e-5f);
  ushort4 gv4 = *(const ushort4*)(gH + (size_t)m*D_ + t*4);
  float g0 = bf2f(gv4.x), g1 = bf2f(gv4.y), g2 = bf2f(gv4.z), g3 = bf2f(gv4.w);
  float4 lw = *(const float4*)(lnw + t*4);
  float4 lb = *(const float4*)(lnb + t*4);
  float z0 = ((v.x-mu)*rstd*lw.x + lb.x)*g0;
  float z1 = ((v.y-mu)*rstd*lw.y + lb.y)*g1;
  float z2 = ((v.z-mu)*rstd*lw.z + lb.z)*g2;
  float z3 = ((v.w-mu)*rstd*lw.w + lb.w)*g3;
  float4 zo; zo.x=z0; zo.y=z1; zo.z=z2; zo.w=z3;
  *(float4*)(z + (size_t)m*D_ + t*4) = zo;
  double zs  = (double)z0 + (double)z1 + (double)z2 + (double)z3;
  double zs2 = (double)z0*z0 + (double)z1*z1 + (double)z2*z2 + (double)z3*z3;
  for (int o = 32; o > 0; o >>= 1) { zs += __shfl_down(zs,o); zs2 += __shfl_down(zs2,o); }
  __syncthreads();
  if (l==0) { lds[w*2]=zs; lds[w*2+1]=zs2; }
  __syncthreads();
  if (t==0) {
    zrow[m*2]   = lds[0]+lds[2]+lds[4]+lds[6];
    zrow[m*2+1] = lds[1]+lds[3]+lds[5]+lds[7];
  }
}

__global__ void k_zstats_final(const double* __restrict__ zrow, float* __restrict__ stats) {
  int b = blockIdx.x, t = threadIdx.x; // 256
  double s=0.0, s2=0.0;
  for (int k=0;k<8;++k) {
    int m = b*2048 + k*256 + t;
    s += zrow[m*2]; s2 += zrow[m*2+1];
  }
  for (int o = 32; o > 0; o >>= 1) { s += __shfl_down(s,o); s2 += __shfl_down(s2,o); }
  __shared__ double lds[8];
  int w = t>>6, l = t&63;
  if (l==0) { lds[w*2]=s; lds[w*2+1]=s2; }
  __syncthreads();
  if (t==0) {
    double ts = lds[0]+lds[2]+lds[4]+lds[6], ts2 = lds[1]+lds[3]+lds[5]+lds[7];
    double inv = 1.0/(double)(N_*D_);
    double mu = ts*inv, var = ts2*inv - mu*mu;
    stats[b*2]   = (float)mu;
    stats[b*2+1] = rsqrtf((float)var + 1e-5f);
  }
}

extern "C" void kernel_launch(void* const* d_in, const int* in_sizes, int n_in,
                              void* d_out, int out_size, void* d_ws, size_t ws_size,
                              hipStream_t stream) {
  const float* x = (const float*)d_in[0];
  Ptr5 W;
  for (int i = 0; i < 5; ++i) W.p[i] = (const float*)d_in[1+i];
  const float* lnw = (const float*)d_in[6];
  const float* lnb = (const float*)d_in[7];

  char* ws = (char*)d_ws;
  float*  xstats = (float*)(ws + 0);
  float*  zstats = (float*)(ws + 64);
  float*  mw     = (float*)(ws + 128);
  float*  invmw  = (float*)(ws + 192);
  double* part1  = (double*)(ws + 256);      // 128*2 doubles
  double* wpart  = (double*)(ws + 2304);     // 80 doubles
  float*  inv1   = (float*)(ws + 3072);      // 4096
  float*  inv2   = (float*)(ws + 19456);     // 4096
  double* zrow   = (double*)(ws + 35840);    // 4096*2
  u16*    wt     = (u16*)(ws + 101376);      // 5*1M bf16 (10.49 MB)
  u16*    qx     = (u16*)(ws + 10587136);    // 4096x1024 bf16 (8.39 MB)
  u16*    qh     = (u16*)(ws + 18975744);
  u16*    kh     = (u16*)(ws + 27364352);
  u16*    vhT    = (u16*)(ws + 35752960);    // [B,H,64,N]
  u16*    gbufH  = (u16*)(ws + 44141568);    // bf16 [M,D] 8.39 MB
  float*  ybuf   = (float*)(ws + 60918784);  // f32 16.78 MB
  float*  zbuf   = (float*)(ws + 77696000);  // f32 16.78 MB
  // aliases (lifetimes verified against dispatch order):
  float*  Mbuf   = (float*)(ws + 77696000);  // = zbuf region; consumed by scan before ln_mul writes z
  u16*    Shi    = (u16*)(ws + 10587136);    // = qx region; qx dead after fused GEMM
  u16*    Slo    = (u16*)(ws + 101376);      // = wt matrices 0-3; dead after fused GEMM; wo weights untouched
  u16*    qz     = qx;

  GammaArg G;
  {
    double l0 = log(1.0/32.0), l1 = log(1.0/512.0);
    for (int h = 0; h < 16; ++h) {
      float t = (float)(l0 + (l1-l0)*((double)h/15.0));
      float gm = 1.0f - expf(t);
      G.lg2[h] = (float)log2((double)gm);
    }
  }

  dim3 b256(256);
  hipLaunchKernelGGL(k_stats_all, dim3(208), b256, 0, stream, x, W, part1, wpart);
  hipLaunchKernelGGL(k_finals, dim3(1), b256, 0, stream, part1, wpart, xstats, mw, invmw);
  hipLaunchKernelGGL(k_ternquant, dim3(9216), b256, 0, stream, W, invmw, wt, x, xstats, qx, inv1);

  hipLaunchKernelGGL(k_gemm_qkvg, dim3(32, 32), b256, 0, stream, qx, wt, inv1, mw, qh, kh, vhT, gbufH);

  hipLaunchKernelGGL(k_state, dim3(32, 32), b256, 0, stream, kh, vhT, Mbuf, G);
  hipLaunchKernelGGL(k_scan, dim3(16, 32), b256, 0, stream, Mbuf, Shi, Slo, G);
  hipLaunchKernelGGL(k_retB, dim3(32, 32), b256, 0, stream, qh, kh, vhT, Shi, Slo, ybuf, G);

  hipLaunchKernelGGL(k_ln_mul, dim3(M_), b256, 0, stream, ybuf, gbufH, lnw, lnb, zbuf, zrow);
  hipLaunchKernelGGL(k_zstats_final, dim3(B_), b256, 0, stream, zrow, zstats);
  hipLaunchKernelGGL(k_quant_rows, dim3(M_), b256, 0, stream, zbuf, zstats, qz, inv2);
  hipLaunchKernelGGL(k_gemm, dim3(32,16), b256, 0, stream, qz, wt + (size_t)4*1048576, inv2, mw, 4, (float*)d_out);
}